// Round 1
// baseline (362.035 us; speedup 1.0000x reference)
//
#include <hip/hip_runtime.h>
#include <stdint.h>

// Problem constants
//  SEQ=1024 (32x32), BSZ=8, EMBED=1024, KD=64, NDIM=16, V=64, R=16384, R2=16
//  DIRS=4, H=64, CDIM=4096

// ---------------------------------------------------------------------------
// K_prep: Ls[a][kn] = log2(sigmoid(A[a][kn])), Bsg[c][kn] = sigmoid(B_c[kn])
// ---------------------------------------------------------------------------
__global__ __launch_bounds__(256) void k_prep(const float* __restrict__ A,
                                              const float* __restrict__ B1,
                                              const float* __restrict__ B2,
                                              float* __restrict__ Ls,
                                              float* __restrict__ Bsg) {
    int g = blockIdx.x * 256 + threadIdx.x;
    if (g < 4096) {
        float a = A[g];
        Ls[g] = -log2f(1.0f + expf(-a));   // log2(sigmoid(a))
    }
    if (g < 2048) {
        float b = (g < 1024) ? B1[g] : B2[g - 1024];
        Bsg[g] = 1.0f / (1.0f + expf(-b));
    }
}

// ---------------------------------------------------------------------------
// K_sel: per (d,r) extract one-hot indices of one_matrix rows.
//   sel = v0 | v1<<6 | v2<<12 | v3<<18 | col<<24 ; coef = product of values
// ---------------------------------------------------------------------------
__global__ __launch_bounds__(256) void k_sel(const float* __restrict__ om,
                                             uint32_t* __restrict__ sel,
                                             float* __restrict__ coef) {
    int gw = (blockIdx.x * 256 + threadIdx.x) >> 6;   // global wave id
    int lane = threadIdx.x & 63;
    int nw = gridDim.x * 4;
    for (int pr = gw; pr < 32768; pr += nw) {
        int d = pr >> 14, r = pr & 16383;
        uint32_t s = 0;
        float cf = 1.0f;
        #pragma unroll
        for (int a = 0; a < 5; ++a) {
            float v = om[((size_t)(d * 5 + a) * 16384 + r) * 64 + lane];
            unsigned long long m = __ballot(v != 0.0f);
            int idx = (m != 0ull) ? __builtin_ctzll(m) : 0;
            float mv = __shfl(v, idx, 64);
            if (m == 0ull) mv = 0.0f;
            if (a < 4) {
                s |= (uint32_t)idx << (6 * a);
                cf *= mv;
            } else {
                if (idx > 1) cf = 0.0f;               // B pad rows are zero
                else { s |= (uint32_t)idx << 24; cf *= mv; }
            }
        }
        if (lane == 0) { sel[pr] = s; coef[pr] = cf; }
    }
}

// ---------------------------------------------------------------------------
// K_w: w[d][p][kn] = sum_{r2<16} coef * exp2(sum_a v_a * Ls[a][kn]) * Bsg[col][kn]
//   block = p (1024), thread handles one d and 8 consecutive kn.
// ---------------------------------------------------------------------------
__global__ __launch_bounds__(256) void k_w(const float* __restrict__ Ls,
                                           const float* __restrict__ Bsg,
                                           const uint32_t* __restrict__ sel,
                                           const float* __restrict__ coef,
                                           float* __restrict__ w) {
    int p = blockIdx.x;
    int t = threadIdx.x;
    int d = t >> 7;
    int j0 = (t & 127) * 8;

    float L[4][8], Bv[2][8], acc[8];
    #pragma unroll
    for (int a = 0; a < 4; ++a) {
        float4 u0 = *(const float4*)(Ls + a * 1024 + j0);
        float4 u1 = *(const float4*)(Ls + a * 1024 + j0 + 4);
        L[a][0] = u0.x; L[a][1] = u0.y; L[a][2] = u0.z; L[a][3] = u0.w;
        L[a][4] = u1.x; L[a][5] = u1.y; L[a][6] = u1.z; L[a][7] = u1.w;
    }
    #pragma unroll
    for (int c = 0; c < 2; ++c) {
        float4 u0 = *(const float4*)(Bsg + c * 1024 + j0);
        float4 u1 = *(const float4*)(Bsg + c * 1024 + j0 + 4);
        Bv[c][0] = u0.x; Bv[c][1] = u0.y; Bv[c][2] = u0.z; Bv[c][3] = u0.w;
        Bv[c][4] = u1.x; Bv[c][5] = u1.y; Bv[c][6] = u1.z; Bv[c][7] = u1.w;
    }
    #pragma unroll
    for (int jj = 0; jj < 8; ++jj) acc[jj] = 0.0f;

    int base = d * 16384 + p * 16;
    #pragma unroll
    for (int r2 = 0; r2 < 16; ++r2) {
        uint32_t s = sel[base + r2];
        float cf = coef[base + r2];
        float f0 = (float)(s & 63u);
        float f1 = (float)((s >> 6) & 63u);
        float f2 = (float)((s >> 12) & 63u);
        float f3 = (float)((s >> 18) & 63u);
        int col = (s >> 24) & 1u;
        #pragma unroll
        for (int jj = 0; jj < 8; ++jj) {
            float ex = f0 * L[0][jj] + f1 * L[1][jj] + f2 * L[2][jj] + f3 * L[3][jj];
            float bs = col ? Bv[1][jj] : Bv[0][jj];
            acc[jj] += cf * bs * exp2f(ex);
        }
    }
    float* dst = w + (size_t)(d * 1024 + p) * 1024 + j0;
    *(float4*)(dst)     = make_float4(acc[0], acc[1], acc[2], acc[3]);
    *(float4*)(dst + 4) = make_float4(acc[4], acc[5], acc[6], acc[7]);
}

// ---------------------------------------------------------------------------
// K_kd: kd4[dir][e][p] = boundary(p) * sum_{d,n} w[d][p][kappa*16+n] * C_d[(h*64+kappa)*16+n] * 0.25
//   with kappa = dir*16+m, e = h*16+m.  block = (kappa, p-tile of 128).
// ---------------------------------------------------------------------------
__global__ __launch_bounds__(256) void k_kd(const float* __restrict__ w,
                                            const float* __restrict__ C1,
                                            const float* __restrict__ C2,
                                            float* __restrict__ kd4) {
    __shared__ float Wl[128 * 33];   // [p][dn] padded
    __shared__ float Ctl[32 * 65];   // [dn][h] padded
    int kap = blockIdx.x;            // 0..63
    int p0 = blockIdx.y * 128;
    int dir = kap >> 4, m = kap & 15;
    int t = threadIdx.x;

    {   // load W tile: 256 segments of 16 floats
        int d = t >> 7, pp = t & 127;
        const float* src = w + ((size_t)(d * 1024 + p0 + pp) * 64 + kap) * 16;
        float* dst = Wl + pp * 33 + d * 16;
        #pragma unroll
        for (int q = 0; q < 4; ++q) {
            float4 v = *(const float4*)(src + q * 4);
            dst[q * 4 + 0] = v.x; dst[q * 4 + 1] = v.y;
            dst[q * 4 + 2] = v.z; dst[q * 4 + 3] = v.w;
        }
    }
    if (t < 128) {  // load C tile (transposed into [dn][h]), scale 1/sqrt(16)
        int d = t >> 6, h = t & 63;
        const float* Cd = d ? C2 : C1;
        const float* src = Cd + (size_t)(h * 64 + kap) * 16;
        #pragma unroll
        for (int q = 0; q < 16; ++q)
            Ctl[(d * 16 + q) * 65 + h] = src[q] * 0.25f;
    }
    __syncthreads();

    int ph = t & 15, hq = t >> 4;
    int pl = ph * 8, h0 = hq * 4;
    float acc[8][4];
    #pragma unroll
    for (int i = 0; i < 8; ++i)
        { acc[i][0] = acc[i][1] = acc[i][2] = acc[i][3] = 0.0f; }

    for (int k = 0; k < 32; ++k) {
        float c0 = Ctl[k * 65 + h0 + 0];
        float c1 = Ctl[k * 65 + h0 + 1];
        float c2 = Ctl[k * 65 + h0 + 2];
        float c3 = Ctl[k * 65 + h0 + 3];
        #pragma unroll
        for (int i = 0; i < 8; ++i) {
            float wv = Wl[(pl + i) * 33 + k];
            acc[i][0] += wv * c0; acc[i][1] += wv * c1;
            acc[i][2] += wv * c2; acc[i][3] += wv * c3;
        }
    }
    #pragma unroll
    for (int j = 0; j < 4; ++j) {
        int h = h0 + j;
        float* dst = kd4 + (size_t)(dir * 1024 + h * 16 + m) * 1024 + p0 + pl;
        #pragma unroll
        for (int qq = 0; qq < 2; ++qq) {
            float vv[4];
            #pragma unroll
            for (int q = 0; q < 4; ++q) {
                int p = p0 + pl + qq * 4 + q;
                int ii = p >> 5, jj = p & 31;
                float f = ((ii == 0) != (jj == 0)) ? 2.0f : 1.0f;  // corner net = 1
                vv[q] = acc[qq * 4 + q][j] * f;
            }
            *(float4*)(dst + qq * 4) = make_float4(vv[0], vv[1], vv[2], vv[3]);
        }
    }
}

// ---------------------------------------------------------------------------
// K_t1: xt[b][e][p] = x[p][b][e]  (tiled transpose)
// ---------------------------------------------------------------------------
__global__ __launch_bounds__(256) void k_t1(const float* __restrict__ x,
                                            float* __restrict__ xt) {
    __shared__ float tile[32][33];
    int p0 = blockIdx.x * 32, e0 = blockIdx.y * 32, b = blockIdx.z;
    int c = threadIdx.x & 31, r4 = (threadIdx.x >> 5) * 4;
    #pragma unroll
    for (int q = 0; q < 4; ++q)
        tile[r4 + q][c] = x[(size_t)((p0 + r4 + q) * 8 + b) * 1024 + e0 + c];
    __syncthreads();
    #pragma unroll
    for (int q = 0; q < 4; ++q)
        xt[(size_t)(b * 1024 + e0 + r4 + q) * 1024 + p0 + c] = tile[c][r4 + q];
}

// ---------------------------------------------------------------------------
// K_conv: per-channel 2D causal conv.  block = e, 8 batches together.
//   y[b,e,i,j] = sum_{u<=i, v<=j} x[b,e,u,v] * ksum[e, i-u, j-v]
//   ksum built in LDS from kd4 with per-direction flips.
// ---------------------------------------------------------------------------
__global__ __launch_bounds__(256) void k_conv(const float* __restrict__ xt,
                                              const float* __restrict__ kd4,
                                              float* __restrict__ yt) {
    __shared__ float xs[8192];        // [p][b], p = u*32+v
    __shared__ float kp[33 * 36];     // padded kernel: kp[(i+1)*36 + (j+1)]
    int e = blockIdx.x;
    int t = threadIdx.x;

    {   // stage x (fully coalesced global reads, scatter into LDS)
        const float4* xt4 = (const float4*)xt;
        #pragma unroll
        for (int b = 0; b < 8; ++b) {
            float4 v = xt4[(size_t)(b * 1024 + e) * 256 + t];
            int p4 = t * 4;
            xs[(p4 + 0) * 8 + b] = v.x;
            xs[(p4 + 1) * 8 + b] = v.y;
            xs[(p4 + 2) * 8 + b] = v.z;
            xs[(p4 + 3) * 8 + b] = v.w;
        }
        for (int idx = t; idx < 33 * 36; idx += 256) kp[idx] = 0.0f;
    }
    __syncthreads();
    {   // build ksum with flips: + kd0[i,j] + kd1[31-i,j] + kd2[i,31-j] + kd3[31-i,31-j]
        int p = t * 4, i = p >> 5, j = p & 31;
        const float* b0 = kd4 + (size_t)e * 1024;
        float4 a0 = *(const float4*)(b0 + i * 32 + j);
        float4 a1 = *(const float4*)(b0 + 1048576 + (31 - i) * 32 + j);
        float4 a2 = *(const float4*)(b0 + 2097152 + i * 32 + (28 - j));
        float4 a3 = *(const float4*)(b0 + 3145728 + (31 - i) * 32 + (28 - j));
        float s0 = a0.x + a1.x + a2.w + a3.w;
        float s1 = a0.y + a1.y + a2.z + a3.z;
        float s2 = a0.z + a1.z + a2.y + a3.y;
        float s3 = a0.w + a1.w + a2.x + a3.x;
        float* kr = kp + (i + 1) * 36 + (j + 1);
        kr[0] = s0; kr[1] = s1; kr[2] = s2; kr[3] = s3;
    }
    __syncthreads();

    // thread -> 2x2 output tile, 8x8 lane quadrants to bound divergence
    int wv = t >> 6, lane = t & 63;
    int ti = ((wv >> 1) << 3) | (lane >> 3);
    int tj = ((wv & 1) << 3) | (lane & 7);
    int i0 = ti * 2, j0 = tj * 2;

    float acc[8][4];
    #pragma unroll
    for (int b = 0; b < 8; ++b)
        { acc[b][0] = acc[b][1] = acc[b][2] = acc[b][3] = 0.0f; }

    for (int u = 0; u <= i0 + 1; ++u) {
        const float* xrow = xs + u * 256;
        const float* krow = kp + (i0 + 1 - u) * 36 + (j0 + 1);
        for (int v = 0; v <= j0 + 1; ++v) {
            const float4* xp = (const float4*)(xrow + v * 8);
            float4 xa = xp[0], xb = xp[1];
            float k00 = krow[-v], k01 = krow[-v + 1];
            float k10 = krow[-v + 36], k11 = krow[-v + 37];
            float xvv[8] = {xa.x, xa.y, xa.z, xa.w, xb.x, xb.y, xb.z, xb.w};
            #pragma unroll
            for (int b = 0; b < 8; ++b) {
                acc[b][0] += xvv[b] * k00;
                acc[b][1] += xvv[b] * k01;
                acc[b][2] += xvv[b] * k10;
                acc[b][3] += xvv[b] * k11;
            }
        }
    }
    #pragma unroll
    for (int b = 0; b < 8; ++b) {
        float* yb = yt + (size_t)(b * 1024 + e) * 1024;
        *(float2*)(yb + i0 * 32 + j0)       = make_float2(acc[b][0], acc[b][1]);
        *(float2*)(yb + (i0 + 1) * 32 + j0) = make_float2(acc[b][2], acc[b][3]);
    }
}

// ---------------------------------------------------------------------------
// K_t2: out[p][b][e] = yt[b][e][p] + x[p][b][e]*omega[e]
// ---------------------------------------------------------------------------
__global__ __launch_bounds__(256) void k_t2(const float* __restrict__ yt,
                                            const float* __restrict__ x,
                                            const float* __restrict__ omega,
                                            float* __restrict__ out) {
    __shared__ float tile[32][33];
    int e0 = blockIdx.x * 32, p0 = blockIdx.y * 32, b = blockIdx.z;
    int c = threadIdx.x & 31, r4 = (threadIdx.x >> 5) * 4;
    #pragma unroll
    for (int q = 0; q < 4; ++q)
        tile[r4 + q][c] = yt[(size_t)(b * 1024 + e0 + r4 + q) * 1024 + p0 + c];
    __syncthreads();
    #pragma unroll
    for (int q = 0; q < 4; ++q) {
        int p = p0 + r4 + q, e = e0 + c;
        size_t oi = (size_t)(p * 8 + b) * 1024 + e;
        out[oi] = tile[c][r4 + q] + x[oi] * omega[e];
    }
}

// ---------------------------------------------------------------------------
extern "C" void kernel_launch(void* const* d_in, const int* in_sizes, int n_in,
                              void* d_out, int out_size, void* d_ws, size_t ws_size,
                              hipStream_t stream) {
    (void)in_sizes; (void)n_in; (void)out_size; (void)ws_size;
    const float* x   = (const float*)d_in[0];
    const float* A   = (const float*)d_in[1];
    const float* B1  = (const float*)d_in[2];
    const float* B2  = (const float*)d_in[3];
    const float* C1  = (const float*)d_in[4];
    const float* C2  = (const float*)d_in[5];
    const float* omg = (const float*)d_in[6];
    const float* om  = (const float*)d_in[7];
    float* out = (float*)d_out;

    float* ws  = (float*)d_ws;
    float* xt  = ws;                       // 8M floats (32 MB)
    float* kd4 = xt + 8 * 1024 * 1024;     // 4M floats (16 MB)
    float* yt  = kd4 + 4 * 1024 * 1024;    // 8M floats (32 MB)
    // small buffers carved inside yt region (dead before k_conv writes yt):
    float* Ls   = yt;                      // 4096
    float* Bsg  = Ls + 4096;               // 2048
    uint32_t* sel = (uint32_t*)(Bsg + 2048);   // 32768 u32
    float* coef = (float*)(sel + 32768);   // 32768
    float* w    = coef + 32768;            // 2,097,152  (total 2.17M < 8M)

    k_t1  <<<dim3(32, 32, 8), 256, 0, stream>>>(x, xt);
    k_prep<<<16, 256, 0, stream>>>(A, B1, B2, Ls, Bsg);
    k_sel <<<256, 256, 0, stream>>>(om, sel, coef);
    k_w   <<<1024, 256, 0, stream>>>(Ls, Bsg, sel, coef, w);
    k_kd  <<<dim3(64, 8), 256, 0, stream>>>(w, C1, C2, kd4);
    k_conv<<<1024, 256, 0, stream>>>(xt, kd4, yt);
    k_t2  <<<dim3(32, 32, 8), 256, 0, stream>>>(yt, x, omg, out);
}

// Round 2
// 269.861 us; speedup vs baseline: 1.3416x; 1.3416x over previous
//
#include <hip/hip_runtime.h>
#include <stdint.h>

// Problem constants
//  SEQ=1024 (32x32), BSZ=8, EMBED=1024, KD=64, NDIM=16, V=64, R=16384, R2=16
//  DIRS=4, H=64, CDIM=4096

typedef __attribute__((ext_vector_type(8))) short short8;   // 8 bf16 (4 VGPRs)
typedef __attribute__((ext_vector_type(4))) float f32x4;    // MFMA accumulator

__device__ inline short f2bf(float f) {   // fp32 -> bf16 RNE
    uint32_t u = __float_as_uint(f);
    uint32_t r = (u + 0x7FFFu + ((u >> 16) & 1u)) >> 16;
    return (short)(r & 0xFFFFu);
}

// ---------------------------------------------------------------------------
// K_prep: Ls[a][kn] = log2(sigmoid(A[a][kn])), Bsg[c][kn] = sigmoid(B_c[kn])
// ---------------------------------------------------------------------------
__global__ __launch_bounds__(256) void k_prep(const float* __restrict__ A,
                                              const float* __restrict__ B1,
                                              const float* __restrict__ B2,
                                              float* __restrict__ Ls,
                                              float* __restrict__ Bsg) {
    int g = blockIdx.x * 256 + threadIdx.x;
    if (g < 4096) {
        float a = A[g];
        Ls[g] = -log2f(1.0f + expf(-a));   // log2(sigmoid(a))
    }
    if (g < 2048) {
        float b = (g < 1024) ? B1[g] : B2[g - 1024];
        Bsg[g] = 1.0f / (1.0f + expf(-b));
    }
}

// ---------------------------------------------------------------------------
// K_sel: per (d,r) extract one-hot indices of one_matrix rows.
// ---------------------------------------------------------------------------
__global__ __launch_bounds__(256) void k_sel(const float* __restrict__ om,
                                             uint32_t* __restrict__ sel,
                                             float* __restrict__ coef) {
    int gw = (blockIdx.x * 256 + threadIdx.x) >> 6;
    int lane = threadIdx.x & 63;
    int nw = gridDim.x * 4;
    for (int pr = gw; pr < 32768; pr += nw) {
        int d = pr >> 14, r = pr & 16383;
        uint32_t s = 0;
        float cf = 1.0f;
        #pragma unroll
        for (int a = 0; a < 5; ++a) {
            float v = om[((size_t)(d * 5 + a) * 16384 + r) * 64 + lane];
            unsigned long long m = __ballot(v != 0.0f);
            int idx = (m != 0ull) ? __builtin_ctzll(m) : 0;
            float mv = __shfl(v, idx, 64);
            if (m == 0ull) mv = 0.0f;
            if (a < 4) {
                s |= (uint32_t)idx << (6 * a);
                cf *= mv;
            } else {
                if (idx > 1) cf = 0.0f;
                else { s |= (uint32_t)idx << 24; cf *= mv; }
            }
        }
        if (lane == 0) { sel[pr] = s; coef[pr] = cf; }
    }
}

// ---------------------------------------------------------------------------
// K_w: w[d][p][kn] = sum_{r2<16} coef * exp2(sum_a v_a * Ls[a][kn]) * Bsg[col][kn]
// ---------------------------------------------------------------------------
__global__ __launch_bounds__(256) void k_w(const float* __restrict__ Ls,
                                           const float* __restrict__ Bsg,
                                           const uint32_t* __restrict__ sel,
                                           const float* __restrict__ coef,
                                           float* __restrict__ w) {
    int p = blockIdx.x;
    int t = threadIdx.x;
    int d = t >> 7;
    int j0 = (t & 127) * 8;

    float L[4][8], Bv[2][8], acc[8];
    #pragma unroll
    for (int a = 0; a < 4; ++a) {
        float4 u0 = *(const float4*)(Ls + a * 1024 + j0);
        float4 u1 = *(const float4*)(Ls + a * 1024 + j0 + 4);
        L[a][0] = u0.x; L[a][1] = u0.y; L[a][2] = u0.z; L[a][3] = u0.w;
        L[a][4] = u1.x; L[a][5] = u1.y; L[a][6] = u1.z; L[a][7] = u1.w;
    }
    #pragma unroll
    for (int c = 0; c < 2; ++c) {
        float4 u0 = *(const float4*)(Bsg + c * 1024 + j0);
        float4 u1 = *(const float4*)(Bsg + c * 1024 + j0 + 4);
        Bv[c][0] = u0.x; Bv[c][1] = u0.y; Bv[c][2] = u0.z; Bv[c][3] = u0.w;
        Bv[c][4] = u1.x; Bv[c][5] = u1.y; Bv[c][6] = u1.z; Bv[c][7] = u1.w;
    }
    #pragma unroll
    for (int jj = 0; jj < 8; ++jj) acc[jj] = 0.0f;

    int base = d * 16384 + p * 16;
    #pragma unroll
    for (int r2 = 0; r2 < 16; ++r2) {
        uint32_t s = sel[base + r2];
        float cf = coef[base + r2];
        float f0 = (float)(s & 63u);
        float f1 = (float)((s >> 6) & 63u);
        float f2 = (float)((s >> 12) & 63u);
        float f3 = (float)((s >> 18) & 63u);
        int col = (s >> 24) & 1u;
        #pragma unroll
        for (int jj = 0; jj < 8; ++jj) {
            float ex = f0 * L[0][jj] + f1 * L[1][jj] + f2 * L[2][jj] + f3 * L[3][jj];
            float bs = col ? Bv[1][jj] : Bv[0][jj];
            acc[jj] += cf * bs * exp2f(ex);
        }
    }
    float* dst = w + (size_t)(d * 1024 + p) * 1024 + j0;
    *(float4*)(dst)     = make_float4(acc[0], acc[1], acc[2], acc[3]);
    *(float4*)(dst + 4) = make_float4(acc[4], acc[5], acc[6], acc[7]);
}

// ---------------------------------------------------------------------------
// K_kd: kd4[dir][e][p] = boundary(p) * sum_{d,n} w[d][p][kap*16+n]*C_d[(h*64+kap)*16+n]/4
// ---------------------------------------------------------------------------
__global__ __launch_bounds__(256) void k_kd(const float* __restrict__ w,
                                            const float* __restrict__ C1,
                                            const float* __restrict__ C2,
                                            float* __restrict__ kd4) {
    __shared__ float Wl[128 * 33];
    __shared__ float Ctl[32 * 65];
    int kap = blockIdx.x;
    int p0 = blockIdx.y * 128;
    int dir = kap >> 4, m = kap & 15;
    int t = threadIdx.x;

    {
        int d = t >> 7, pp = t & 127;
        const float* src = w + ((size_t)(d * 1024 + p0 + pp) * 64 + kap) * 16;
        float* dst = Wl + pp * 33 + d * 16;
        #pragma unroll
        for (int q = 0; q < 4; ++q) {
            float4 v = *(const float4*)(src + q * 4);
            dst[q * 4 + 0] = v.x; dst[q * 4 + 1] = v.y;
            dst[q * 4 + 2] = v.z; dst[q * 4 + 3] = v.w;
        }
    }
    if (t < 128) {
        int d = t >> 6, h = t & 63;
        const float* Cd = d ? C2 : C1;
        const float* src = Cd + (size_t)(h * 64 + kap) * 16;
        #pragma unroll
        for (int q = 0; q < 16; ++q)
            Ctl[(d * 16 + q) * 65 + h] = src[q] * 0.25f;
    }
    __syncthreads();

    int ph = t & 15, hq = t >> 4;
    int pl = ph * 8, h0 = hq * 4;
    float acc[8][4];
    #pragma unroll
    for (int i = 0; i < 8; ++i)
        { acc[i][0] = acc[i][1] = acc[i][2] = acc[i][3] = 0.0f; }

    for (int k = 0; k < 32; ++k) {
        float c0 = Ctl[k * 65 + h0 + 0];
        float c1 = Ctl[k * 65 + h0 + 1];
        float c2 = Ctl[k * 65 + h0 + 2];
        float c3 = Ctl[k * 65 + h0 + 3];
        #pragma unroll
        for (int i = 0; i < 8; ++i) {
            float wv = Wl[(pl + i) * 33 + k];
            acc[i][0] += wv * c0; acc[i][1] += wv * c1;
            acc[i][2] += wv * c2; acc[i][3] += wv * c3;
        }
    }
    #pragma unroll
    for (int j = 0; j < 4; ++j) {
        int h = h0 + j;
        float* dst = kd4 + (size_t)(dir * 1024 + h * 16 + m) * 1024 + p0 + pl;
        #pragma unroll
        for (int qq = 0; qq < 2; ++qq) {
            float vv[4];
            #pragma unroll
            for (int q = 0; q < 4; ++q) {
                int p = p0 + pl + qq * 4 + q;
                int ii = p >> 5, jj = p & 31;
                float f = ((ii == 0) != (jj == 0)) ? 2.0f : 1.0f;
                vv[q] = acc[qq * 4 + q][j] * f;
            }
            *(float4*)(dst + qq * 4) = make_float4(vv[0], vv[1], vv[2], vv[3]);
        }
    }
}

// ---------------------------------------------------------------------------
// K_t1: xt[b][e][p] = x[p][b][e]
// ---------------------------------------------------------------------------
__global__ __launch_bounds__(256) void k_t1(const float* __restrict__ x,
                                            float* __restrict__ xt) {
    __shared__ float tile[32][33];
    int p0 = blockIdx.x * 32, e0 = blockIdx.y * 32, b = blockIdx.z;
    int c = threadIdx.x & 31, r4 = (threadIdx.x >> 5) * 4;
    #pragma unroll
    for (int q = 0; q < 4; ++q)
        tile[r4 + q][c] = x[(size_t)((p0 + r4 + q) * 8 + b) * 1024 + e0 + c];
    __syncthreads();
    #pragma unroll
    for (int q = 0; q < 4; ++q)
        xt[(size_t)(b * 1024 + e0 + r4 + q) * 1024 + p0 + c] = tile[c][r4 + q];
}

// ---------------------------------------------------------------------------
// K_conv (MFMA): per-channel causal 2D conv as Toeplitz GEMM.
//   Y[i][j][b] += sum_v kimg[di=i-u][j-v] * X[u][v][b], per (i,u) pair:
//   M=32(j, two 16-tiles), K=32(v), N=8(b, padded to 16), mfma_f32_16x16x32_bf16.
//   A-fragment = one aligned ds_read_b128 from 8 shift-staggered reversed
//   copies of each kernel row (Krev8). B-fragment = ds_read_b128 from Xt[u][b][v].
//   Wave w owns output rows i == w (mod 4)  -> wave-uniform loop bounds.
// ---------------------------------------------------------------------------
__global__ __launch_bounds__(256) void k_conv(const float* __restrict__ xt,
                                              const float* __restrict__ kd4,
                                              float* __restrict__ yt) {
    // region0 (32896 B): Krev8[di 32][s 8][c 64] bf16 (32768 B), later Ybuf[8][1028] f32
    // region1 (16896 B): Xt[u 32][b 8][v 32] bf16 (+pad for n>=8 garbage reads)
    __shared__ __align__(16) char smem[32896 + 16896];
    char* krev = smem;
    float* ybuf = (float*)smem;
    char* xtl = smem + 32896;

    int e = blockIdx.x;
    int t = threadIdx.x;
    int lane = t & 63, wv = t >> 6;
    int n = lane & 15, q = lane >> 4;

    // ---- zero region0 (Krev8 needs zero padding everywhere not written) ----
    {
        f32x4 z = {0.f, 0.f, 0.f, 0.f};
        #pragma unroll
        for (int k = 0; k < 8; ++k)
            *(f32x4*)(smem + (t + k * 256) * 16) = z;
        if (t < 8) *(f32x4*)(smem + (2048 + t) * 16) = z;
    }

    // ---- load x (coalesced), pack to bf16 ----
    uint32_t xpack[8][2];
    {
        const float4* xt4 = (const float4*)xt;
        #pragma unroll
        for (int b = 0; b < 8; ++b) {
            float4 v = xt4[(size_t)(b * 1024 + e) * 256 + t];
            xpack[b][0] = (uint32_t)(uint16_t)f2bf(v.x) | ((uint32_t)(uint16_t)f2bf(v.y) << 16);
            xpack[b][1] = (uint32_t)(uint16_t)f2bf(v.z) | ((uint32_t)(uint16_t)f2bf(v.w) << 16);
        }
    }

    // ---- flip-sum 4 kernel pixels (fp32) for this thread ----
    int pi = t >> 3, pj = (t & 7) * 4;       // pixel row, col base (4 cols)
    float s0, s1, s2, s3;
    {
        const float* b0 = kd4 + (size_t)e * 1024;
        float4 a0 = *(const float4*)(b0 + pi * 32 + pj);
        float4 a1 = *(const float4*)(b0 + 1048576 + (31 - pi) * 32 + pj);
        float4 a2 = *(const float4*)(b0 + 2097152 + pi * 32 + (28 - pj));
        float4 a3 = *(const float4*)(b0 + 3145728 + (31 - pi) * 32 + (28 - pj));
        s0 = a0.x + a1.x + a2.w + a3.w;
        s1 = a0.y + a1.y + a2.z + a3.z;
        s2 = a0.z + a1.z + a2.y + a3.y;
        s3 = a0.w + a1.w + a2.x + a3.x;
    }

    // ---- write Xt (independent of region0 zeroing) ----
    #pragma unroll
    for (int b = 0; b < 8; ++b) {
        uint32_t* dst = (uint32_t*)(xtl + (t >> 3) * 512 + b * 64 + (t & 7) * 8);
        dst[0] = xpack[b][0]; dst[1] = xpack[b][1];
    }

    __syncthreads();   // zeroing of Krev8 complete

    // ---- scatter kernel pixels into the 8 shifted reversed copies ----
    {
        short k0 = f2bf(s0), k1 = f2bf(s1), k2 = f2bf(s2), k3 = f2bf(s3);
        short* kr = (short*)krev + pi * 512;          // 8 s-rows of 64
        #pragma unroll
        for (int s = 0; s < 8; ++s) {
            int c = s * 64 + (31 + s - pj);           // Krev8[di][s][31+s-j] = kimg[di][j]
            kr[c]     = k0;
            kr[c - 1] = k1;
            kr[c - 2] = k2;
            kr[c - 3] = k3;
        }
    }
    __syncthreads();

    // ---- main MFMA loop ----
    // A-frag lane addr: A[m=lane&15][k=8q+jj] = kimg[di][A0-jj], A0 = jo+m-8q.
    // Krev8[di][s][c] = kimg[di][31+s-c]; need c0 = 31+s-A0 multiple of 8.
    int A0_0 = n - 8 * q;
    int A0_1 = 16 + n - 8 * q;
    int sh0 = (A0_0 + 33) & 7, sh1 = (A0_1 + 33) & 7;
    int off0 = sh0 * 128 + (31 + sh0 - A0_0) * 2;
    int off1 = sh1 * 128 + (31 + sh1 - A0_1) * 2;
    int boff = n * 64 + q * 16;

    f32x4 acc0[8], acc1[8];
    #pragma unroll
    for (int ii = 0; ii < 8; ++ii) {
        acc0[ii] = (f32x4){0.f, 0.f, 0.f, 0.f};
        acc1[ii] = (f32x4){0.f, 0.f, 0.f, 0.f};
    }

    for (int di = 0; di <= wv + 28; ++di) {
        short8 a0 = *(const short8*)(krev + di * 1024 + off0);
        short8 a1 = *(const short8*)(krev + di * 1024 + off1);
        #pragma unroll
        for (int ii = 0; ii < 8; ++ii) {
            if (wv + 4 * ii >= di) {                  // wave-uniform
                int u = wv + 4 * ii - di;
                short8 bb = *(const short8*)(xtl + u * 512 + boff);
                acc0[ii] = __builtin_amdgcn_mfma_f32_16x16x32_bf16(a0, bb, acc0[ii], 0, 0, 0);
                acc1[ii] = __builtin_amdgcn_mfma_f32_16x16x32_bf16(a1, bb, acc1[ii], 0, 0, 0);
            }
        }
    }

    __syncthreads();   // Krev8 dead; region0 becomes Ybuf

    // ---- epilogue: D[m][n]: row m = 4q+r, col n -> p = i*32 + jo + 4q + r, b = n
    if (n < 8) {
        #pragma unroll
        for (int ii = 0; ii < 8; ++ii) {
            int i = wv + 4 * ii;
            int pb = i * 32 + q * 4;
            #pragma unroll
            for (int r = 0; r < 4; ++r) {
                ybuf[n * 1028 + pb + r]      = acc0[ii][r];
                ybuf[n * 1028 + pb + 16 + r] = acc1[ii][r];
            }
        }
    }
    __syncthreads();

    {
        float4* yt4 = (float4*)yt;
        #pragma unroll
        for (int b = 0; b < 8; ++b) {
            float4 v = *(const float4*)(ybuf + b * 1028 + t * 4);
            yt4[(size_t)(b * 1024 + e) * 256 + t] = v;
        }
    }
}

// ---------------------------------------------------------------------------
// K_t2: out[p][b][e] = yt[b][e][p] + x[p][b][e]*omega[e]
// ---------------------------------------------------------------------------
__global__ __launch_bounds__(256) void k_t2(const float* __restrict__ yt,
                                            const float* __restrict__ x,
                                            const float* __restrict__ omega,
                                            float* __restrict__ out) {
    __shared__ float tile[32][33];
    int e0 = blockIdx.x * 32, p0 = blockIdx.y * 32, b = blockIdx.z;
    int c = threadIdx.x & 31, r4 = (threadIdx.x >> 5) * 4;
    #pragma unroll
    for (int q = 0; q < 4; ++q)
        tile[r4 + q][c] = yt[(size_t)(b * 1024 + e0 + r4 + q) * 1024 + p0 + c];
    __syncthreads();
    #pragma unroll
    for (int q = 0; q < 4; ++q) {
        int p = p0 + r4 + q, e = e0 + c;
        size_t oi = (size_t)(p * 8 + b) * 1024 + e;
        out[oi] = tile[c][r4 + q] + x[oi] * omega[e];
    }
}

// ---------------------------------------------------------------------------
extern "C" void kernel_launch(void* const* d_in, const int* in_sizes, int n_in,
                              void* d_out, int out_size, void* d_ws, size_t ws_size,
                              hipStream_t stream) {
    (void)in_sizes; (void)n_in; (void)out_size; (void)ws_size;
    const float* x   = (const float*)d_in[0];
    const float* A   = (const float*)d_in[1];
    const float* B1  = (const float*)d_in[2];
    const float* B2  = (const float*)d_in[3];
    const float* C1  = (const float*)d_in[4];
    const float* C2  = (const float*)d_in[5];
    const float* omg = (const float*)d_in[6];
    const float* om  = (const float*)d_in[7];
    float* out = (float*)d_out;

    float* ws  = (float*)d_ws;
    float* xt  = ws;                       // 8M floats (32 MB)
    float* kd4 = xt + 8 * 1024 * 1024;     // 4M floats (16 MB)
    float* yt  = kd4 + 4 * 1024 * 1024;    // 8M floats (32 MB)
    // small buffers carved inside yt region (dead before k_conv writes yt):
    float* Ls   = yt;                      // 4096
    float* Bsg  = Ls + 4096;               // 2048
    uint32_t* sel = (uint32_t*)(Bsg + 2048);   // 32768 u32
    float* coef = (float*)(sel + 32768);   // 32768
    float* w    = coef + 32768;            // 2,097,152

    k_t1  <<<dim3(32, 32, 8), 256, 0, stream>>>(x, xt);
    k_prep<<<16, 256, 0, stream>>>(A, B1, B2, Ls, Bsg);
    k_sel <<<256, 256, 0, stream>>>(om, sel, coef);
    k_w   <<<1024, 256, 0, stream>>>(Ls, Bsg, sel, coef, w);
    k_kd  <<<dim3(64, 8), 256, 0, stream>>>(w, C1, C2, kd4);
    k_conv<<<1024, 256, 0, stream>>>(xt, kd4, yt);
    k_t2  <<<dim3(32, 32, 8), 256, 0, stream>>>(yt, x, omg, out);
}

// Round 3
// 257.739 us; speedup vs baseline: 1.4047x; 1.0470x over previous
//
#include <hip/hip_runtime.h>
#include <stdint.h>

// Problem constants
//  SEQ=1024 (32x32), BSZ=8, EMBED=1024, KD=64, NDIM=16, V=64, R=16384, R2=16
//  DIRS=4, H=64, CDIM=4096

typedef __attribute__((ext_vector_type(8))) short short8;   // 8 bf16 (4 VGPRs)
typedef __attribute__((ext_vector_type(4))) float f32x4;    // MFMA accumulator

__device__ inline uint16_t f2bf(float f) {   // fp32 -> bf16 RNE
    uint32_t u = __float_as_uint(f);
    uint32_t r = (u + 0x7FFFu + ((u >> 16) & 1u)) >> 16;
    return (uint16_t)r;
}
__device__ inline float bf2f(uint16_t v) {
    return __uint_as_float((uint32_t)v << 16);
}
__device__ inline uint32_t packbf(float a, float b) {
    return (uint32_t)f2bf(a) | ((uint32_t)f2bf(b) << 16);
}

// ---------------------------------------------------------------------------
// K_sel: per (d,r) extract one-hot indices of one_matrix rows.
// ---------------------------------------------------------------------------
__global__ __launch_bounds__(256) void k_sel(const float* __restrict__ om,
                                             uint32_t* __restrict__ sel,
                                             float* __restrict__ coef) {
    int gw = (blockIdx.x * 256 + threadIdx.x) >> 6;
    int lane = threadIdx.x & 63;
    int nw = gridDim.x * 4;
    for (int pr = gw; pr < 32768; pr += nw) {
        int d = pr >> 14, r = pr & 16383;
        uint32_t s = 0;
        float cf = 1.0f;
        #pragma unroll
        for (int a = 0; a < 5; ++a) {
            float v = om[((size_t)(d * 5 + a) * 16384 + r) * 64 + lane];
            unsigned long long m = __ballot(v != 0.0f);
            int idx = (m != 0ull) ? __builtin_ctzll(m) : 0;
            float mv = __shfl(v, idx, 64);
            if (m == 0ull) mv = 0.0f;
            if (a < 4) {
                s |= (uint32_t)idx << (6 * a);
                cf *= mv;
            } else {
                if (idx > 1) cf = 0.0f;
                else { s |= (uint32_t)idx << 24; cf *= mv; }
            }
        }
        if (lane == 0) { sel[pr] = s; coef[pr] = cf; }
    }
}

// ---------------------------------------------------------------------------
// K_w (merged prep): w[d][p][kn] = sum_{r2} coef * exp2(sum_a v_a*log2sig(A_a)) * sig(B_col)
// ---------------------------------------------------------------------------
__global__ __launch_bounds__(256) void k_w(const float* __restrict__ A,
                                           const float* __restrict__ B1,
                                           const float* __restrict__ B2,
                                           const uint32_t* __restrict__ sel,
                                           const float* __restrict__ coef,
                                           float* __restrict__ w) {
    int p = blockIdx.x;
    int t = threadIdx.x;
    int d = t >> 7;
    int j0 = (t & 127) * 8;

    float L[4][8], Bv[2][8], acc[8];
    #pragma unroll
    for (int a = 0; a < 4; ++a) {
        float4 u0 = *(const float4*)(A + a * 1024 + j0);
        float4 u1 = *(const float4*)(A + a * 1024 + j0 + 4);
        float tmp[8] = {u0.x, u0.y, u0.z, u0.w, u1.x, u1.y, u1.z, u1.w};
        #pragma unroll
        for (int jj = 0; jj < 8; ++jj)
            L[a][jj] = -log2f(1.0f + expf(-tmp[jj]));
    }
    {
        float4 u0 = *(const float4*)(B1 + j0);
        float4 u1 = *(const float4*)(B1 + j0 + 4);
        float4 v0 = *(const float4*)(B2 + j0);
        float4 v1 = *(const float4*)(B2 + j0 + 4);
        float t1[8] = {u0.x, u0.y, u0.z, u0.w, u1.x, u1.y, u1.z, u1.w};
        float t2[8] = {v0.x, v0.y, v0.z, v0.w, v1.x, v1.y, v1.z, v1.w};
        #pragma unroll
        for (int jj = 0; jj < 8; ++jj) {
            Bv[0][jj] = 1.0f / (1.0f + expf(-t1[jj]));
            Bv[1][jj] = 1.0f / (1.0f + expf(-t2[jj]));
        }
    }
    #pragma unroll
    for (int jj = 0; jj < 8; ++jj) acc[jj] = 0.0f;

    int base = d * 16384 + p * 16;
    #pragma unroll
    for (int r2 = 0; r2 < 16; ++r2) {
        uint32_t s = sel[base + r2];
        float cf = coef[base + r2];
        float f0 = (float)(s & 63u);
        float f1 = (float)((s >> 6) & 63u);
        float f2 = (float)((s >> 12) & 63u);
        float f3 = (float)((s >> 18) & 63u);
        int col = (s >> 24) & 1u;
        #pragma unroll
        for (int jj = 0; jj < 8; ++jj) {
            float ex = f0 * L[0][jj] + f1 * L[1][jj] + f2 * L[2][jj] + f3 * L[3][jj];
            float bs = col ? Bv[1][jj] : Bv[0][jj];
            acc[jj] += cf * bs * exp2f(ex);
        }
    }
    float* dst = w + (size_t)(d * 1024 + p) * 1024 + j0;
    *(float4*)(dst)     = make_float4(acc[0], acc[1], acc[2], acc[3]);
    *(float4*)(dst + 4) = make_float4(acc[4], acc[5], acc[6], acc[7]);
}

// ---------------------------------------------------------------------------
// K_kd: kd4b[dir][e][p] (bf16) = boundary(p) * sum_{d,n} w*C/4
// ---------------------------------------------------------------------------
__global__ __launch_bounds__(256) void k_kd(const float* __restrict__ w,
                                            const float* __restrict__ C1,
                                            const float* __restrict__ C2,
                                            uint16_t* __restrict__ kd4b) {
    __shared__ float Wl[128 * 33];
    __shared__ float Ctl[32 * 65];
    int kap = blockIdx.x;
    int p0 = blockIdx.y * 128;
    int dir = kap >> 4, m = kap & 15;
    int t = threadIdx.x;

    {
        int d = t >> 7, pp = t & 127;
        const float* src = w + ((size_t)(d * 1024 + p0 + pp) * 64 + kap) * 16;
        float* dst = Wl + pp * 33 + d * 16;
        #pragma unroll
        for (int q = 0; q < 4; ++q) {
            float4 v = *(const float4*)(src + q * 4);
            dst[q * 4 + 0] = v.x; dst[q * 4 + 1] = v.y;
            dst[q * 4 + 2] = v.z; dst[q * 4 + 3] = v.w;
        }
    }
    if (t < 128) {
        int d = t >> 6, h = t & 63;
        const float* Cd = d ? C2 : C1;
        const float* src = Cd + (size_t)(h * 64 + kap) * 16;
        #pragma unroll
        for (int q = 0; q < 16; ++q)
            Ctl[(d * 16 + q) * 65 + h] = src[q] * 0.25f;
    }
    __syncthreads();

    int ph = t & 15, hq = t >> 4;
    int pl = ph * 8, h0 = hq * 4;
    float acc[8][4];
    #pragma unroll
    for (int i = 0; i < 8; ++i)
        { acc[i][0] = acc[i][1] = acc[i][2] = acc[i][3] = 0.0f; }

    for (int k = 0; k < 32; ++k) {
        float c0 = Ctl[k * 65 + h0 + 0];
        float c1 = Ctl[k * 65 + h0 + 1];
        float c2 = Ctl[k * 65 + h0 + 2];
        float c3 = Ctl[k * 65 + h0 + 3];
        #pragma unroll
        for (int i = 0; i < 8; ++i) {
            float wv = Wl[(pl + i) * 33 + k];
            acc[i][0] += wv * c0; acc[i][1] += wv * c1;
            acc[i][2] += wv * c2; acc[i][3] += wv * c3;
        }
    }
    #pragma unroll
    for (int j = 0; j < 4; ++j) {
        int h = h0 + j;
        uint32_t pk[4];
        #pragma unroll
        for (int qq = 0; qq < 4; ++qq) {
            float v0, v1;
            #pragma unroll
            for (int z = 0; z < 2; ++z) {
                int p = p0 + pl + qq * 2 + z;
                int ii = p >> 5, jj = p & 31;
                float f = ((ii == 0) != (jj == 0)) ? 2.0f : 1.0f;
                float val = acc[qq * 2 + z][j] * f;
                if (z == 0) v0 = val; else v1 = val;
            }
            pk[qq] = packbf(v0, v1);
        }
        uint16_t* dst = kd4b + ((size_t)(dir * 1024 + h * 16 + m)) * 1024 + p0 + pl;
        *(uint4*)dst = make_uint4(pk[0], pk[1], pk[2], pk[3]);
    }
}

// ---------------------------------------------------------------------------
// K_t1: xtb[e][u][b][v] (bf16) = x[u*32+v][b][e] — packed in conv's LDS layout
// ---------------------------------------------------------------------------
__global__ __launch_bounds__(256) void k_t1(const float* __restrict__ x,
                                            uint16_t* __restrict__ xtb) {
    __shared__ float tile[256 * 36];   // [pv=v*8+b][ec], stride 36 (bank-safe both phases)
    int u = blockIdx.x, e0 = blockIdx.y * 32;
    int t = threadIdx.x;
    int ec = t & 31, vb = t >> 5;
    for (int c = 0; c < 32; ++c) {
        int pv = c * 8 + vb;               // v = pv>>3, b = pv&7
        int v = pv >> 3, b = pv & 7;
        tile[pv * 36 + ec] = x[(size_t)((u * 32 + v) * 8 + b) * 1024 + e0 + ec];
    }
    __syncthreads();
    int er = t >> 3, seg = t & 7;          // e-row within tile, b = seg
    uint32_t pk[16];
    #pragma unroll
    for (int k2 = 0; k2 < 16; ++k2) {
        float f0 = tile[((2 * k2) * 8 + seg) * 36 + er];
        float f1 = tile[((2 * k2 + 1) * 8 + seg) * 36 + er];
        pk[k2] = packbf(f0, f1);
    }
    uint16_t* dst = xtb + (size_t)(e0 + er) * 8192 + u * 256 + seg * 32;
    uint4* d4 = (uint4*)dst;
    d4[0] = make_uint4(pk[0], pk[1], pk[2], pk[3]);
    d4[1] = make_uint4(pk[4], pk[5], pk[6], pk[7]);
    d4[2] = make_uint4(pk[8], pk[9], pk[10], pk[11]);
    d4[3] = make_uint4(pk[12], pk[13], pk[14], pk[15]);
}

// ---------------------------------------------------------------------------
// K_conv (MFMA): per-channel causal 2D conv as Toeplitz GEMM.
//   Krev[di][s(8)][c(48, stride 52 shorts)] bf16: Krev[di][s][c] = kimg[di][31+s-c]
//   Xt[u(32)][b(8)][v(32)] bf16 staged by plain 16B/lane copies (pre-packed xtb).
//   Static unrolled (g,dd) schedule; rows u<16 register-cached.
// ---------------------------------------------------------------------------
__global__ __launch_bounds__(256) void k_conv(const uint16_t* __restrict__ xtb,
                                              const uint16_t* __restrict__ kd4b,
                                              float* __restrict__ yt) {
    __shared__ __align__(16) char smem[26624 + 16384];  // Krev 26624 + Xt 16384
    const int KROW = 832;   // 8 s-rows * 104 B
    const int SROW = 104;   // 52 shorts per s-row (48 used + 4 pad)
    char* xtl = smem + 26624;

    int e = blockIdx.x;
    int t = threadIdx.x;
    int lane = t & 63, wv = t >> 6;
    int n = lane & 15, q = lane >> 4, nn = n & 7;

    // zero Krev (26624 B = 1664 x 16B)
    {
        f32x4 z = {0.f, 0.f, 0.f, 0.f};
        for (int idx = t; idx < 1664; idx += 256)
            *(f32x4*)(smem + idx * 16) = z;
    }
    // stage Xt: 16 KB contiguous copy (conflict-free, no repack)
    {
        const uint4* src = (const uint4*)(xtb + (size_t)e * 8192);
        #pragma unroll
        for (int r = 0; r < 4; ++r) {
            uint4 v = src[r * 256 + t];
            *(uint4*)(xtl + (r * 256 + t) * 16) = v;
        }
    }
    // flip-sum 4 kernel pixels
    int pi = t >> 3, pj = (t & 7) * 4;
    float s0, s1, s2, s3;
    {
        const uint16_t* b0 = kd4b + (size_t)e * 1024;
        ushort4 a0 = *(const ushort4*)(b0 + pi * 32 + pj);
        ushort4 a1 = *(const ushort4*)(b0 + (1 << 20) + (31 - pi) * 32 + pj);
        ushort4 a2 = *(const ushort4*)(b0 + (2 << 20) + pi * 32 + (28 - pj));
        ushort4 a3 = *(const ushort4*)(b0 + (3 << 20) + (31 - pi) * 32 + (28 - pj));
        s0 = bf2f(a0.x) + bf2f(a1.x) + bf2f(a2.w) + bf2f(a3.w);
        s1 = bf2f(a0.y) + bf2f(a1.y) + bf2f(a2.z) + bf2f(a3.z);
        s2 = bf2f(a0.z) + bf2f(a1.z) + bf2f(a2.y) + bf2f(a3.y);
        s3 = bf2f(a0.w) + bf2f(a1.w) + bf2f(a2.x) + bf2f(a3.x);
    }
    __syncthreads();   // zeroing complete

    // scatter into 8 shift-staggered reversed copies
    {
        uint16_t k0 = f2bf(s0), k1 = f2bf(s1), k2 = f2bf(s2), k3 = f2bf(s3);
        #pragma unroll
        for (int s = 0; s < 8; ++s) {
            uint16_t* row = (uint16_t*)(smem + pi * KROW + s * SROW);
            int c = 31 + s - pj;           // c-3..c within [s, 38] ⊂ [0,48)
            row[c]     = k0;
            row[c - 1] = k1;
            row[c - 2] = k2;
            row[c - 3] = k3;
        }
    }
    __syncthreads();

    // lane offsets into Krev rows (16B-aligned by construction of sh)
    int A0 = n - 8 * q;          // tile0 leading index; < -8 => all-zero fragment
    int A1 = A0 + 16;            // tile1, always in [-8, 31]
    int sh1 = (A1 + 9) & 7;
    int off1 = sh1 * SROW + (31 + sh1 - A1) * 2;
    int off0;
    if (A0 >= -8) {
        int sh0 = (A0 + 9) & 7;
        off0 = sh0 * SROW + (31 + sh0 - A0) * 2;
    } else {
        off0 = 80;               // s=0, c=40..47: guaranteed-zero 16B region
    }
    int boff = nn * 64 + q * 16;

    // register-cache input rows 0..15
    short8 Breg[16];
    #pragma unroll
    for (int u = 0; u < 16; ++u)
        Breg[u] = *(const short8*)(xtl + u * 512 + boff);

    f32x4 acc0[8], acc1[8];
    #pragma unroll
    for (int ii = 0; ii < 8; ++ii) {
        acc0[ii] = (f32x4){0.f, 0.f, 0.f, 0.f};
        acc1[ii] = (f32x4){0.f, 0.f, 0.f, 0.f};
    }

    // phase 1: di = wv-dd (dd=0..wv), all 8 ii active, u = dd+4*ii
    #pragma unroll
    for (int dd = 0; dd < 4; ++dd) {
        if (dd <= wv) {
            const char* krow = smem + (wv - dd) * KROW;
            short8 a0 = *(const short8*)(krow + off0);
            short8 a1 = *(const short8*)(krow + off1);
            #pragma unroll
            for (int ii = 0; ii < 8; ++ii) {
                short8 bb = (ii < 4) ? Breg[dd + 4 * ii]
                                     : *(const short8*)(xtl + (dd + 4 * ii) * 512 + boff);
                acc0[ii] = __builtin_amdgcn_mfma_f32_16x16x32_bf16(a0, bb, acc0[ii], 0, 0, 0);
                acc1[ii] = __builtin_amdgcn_mfma_f32_16x16x32_bf16(a1, bb, acc1[ii], 0, 0, 0);
            }
        }
    }
    // phase 2: g=1..7, dd=0..3: di = wv+4g-3+dd, ii = g..7, u = 4(ii-g)+3-dd
    #pragma unroll
    for (int g = 1; g <= 7; ++g) {
        #pragma unroll
        for (int dd = 0; dd < 4; ++dd) {
            const char* krow = smem + (wv + 4 * g - 3 + dd) * KROW;
            short8 a0 = *(const short8*)(krow + off0);
            short8 a1 = *(const short8*)(krow + off1);
            #pragma unroll
            for (int ii = g; ii < 8; ++ii) {
                int u = 4 * (ii - g) + 3 - dd;
                short8 bb = (ii - g < 4) ? Breg[u]
                                         : *(const short8*)(xtl + u * 512 + boff);
                acc0[ii] = __builtin_amdgcn_mfma_f32_16x16x32_bf16(a0, bb, acc0[ii], 0, 0, 0);
                acc1[ii] = __builtin_amdgcn_mfma_f32_16x16x32_bf16(a1, bb, acc1[ii], 0, 0, 0);
            }
        }
    }

    // epilogue: direct stores.  D row m=4q+r -> p = i*32 + tile*16 + 4q+r, col n = b
    if (n < 8) {
        float* base = yt + ((size_t)(n * 1024 + e)) * 1024 + q * 4;
        #pragma unroll
        for (int ii = 0; ii < 8; ++ii) {
            int i = wv + 4 * ii;
            *(float4*)(base + i * 32)      = *(float4*)&acc0[ii];
            *(float4*)(base + i * 32 + 16) = *(float4*)&acc1[ii];
        }
    }
}

// ---------------------------------------------------------------------------
// K_t2: out[p][b][e] = yt[b][e][p] + x[p][b][e]*omega[e]
// ---------------------------------------------------------------------------
__global__ __launch_bounds__(256) void k_t2(const float* __restrict__ yt,
                                            const float* __restrict__ x,
                                            const float* __restrict__ omega,
                                            float* __restrict__ out) {
    __shared__ float tile[32][33];
    int e0 = blockIdx.x * 32, p0 = blockIdx.y * 32, b = blockIdx.z;
    int c = threadIdx.x & 31, r4 = (threadIdx.x >> 5) * 4;
    #pragma unroll
    for (int q = 0; q < 4; ++q)
        tile[r4 + q][c] = yt[(size_t)(b * 1024 + e0 + r4 + q) * 1024 + p0 + c];
    __syncthreads();
    #pragma unroll
    for (int q = 0; q < 4; ++q) {
        int p = p0 + r4 + q, e = e0 + c;
        size_t oi = (size_t)(p * 8 + b) * 1024 + e;
        out[oi] = tile[c][r4 + q] + x[oi] * omega[e];
    }
}

// ---------------------------------------------------------------------------
extern "C" void kernel_launch(void* const* d_in, const int* in_sizes, int n_in,
                              void* d_out, int out_size, void* d_ws, size_t ws_size,
                              hipStream_t stream) {
    (void)in_sizes; (void)n_in; (void)out_size; (void)ws_size;
    const float* x   = (const float*)d_in[0];
    const float* A   = (const float*)d_in[1];
    const float* B1  = (const float*)d_in[2];
    const float* B2  = (const float*)d_in[3];
    const float* C1  = (const float*)d_in[4];
    const float* C2  = (const float*)d_in[5];
    const float* omg = (const float*)d_in[6];
    const float* om  = (const float*)d_in[7];
    float* out = (float*)d_out;

    float* ws  = (float*)d_ws;
    uint16_t* xtb  = (uint16_t*)ws;                 // 8M shorts (16 MB) = 4M float slots
    uint16_t* kd4b = (uint16_t*)(ws + 4194304);     // 4M shorts (8 MB)  = 2M float slots
    float* yt = ws + 6291456;                       // 8M floats (32 MB)
    // smalls carved inside yt region (dead before k_conv writes yt):
    uint32_t* sel = (uint32_t*)yt;                  // 32768 u32
    float* coef = (float*)(sel + 32768);            // 32768
    float* w    = coef + 32768;                     // 2,097,152

    k_t1  <<<dim3(32, 32), 256, 0, stream>>>(x, xtb);
    k_sel <<<256, 256, 0, stream>>>(om, sel, coef);
    k_w   <<<1024, 256, 0, stream>>>(A, B1, B2, sel, coef, w);
    k_kd  <<<dim3(64, 8), 256, 0, stream>>>(w, C1, C2, kd4b);
    k_conv<<<1024, 256, 0, stream>>>(xtb, kd4b, yt);
    k_t2  <<<dim3(32, 32, 8), 256, 0, stream>>>(yt, x, omg, out);
}

// Round 4
// 242.517 us; speedup vs baseline: 1.4928x; 1.0628x over previous
//
#include <hip/hip_runtime.h>
#include <stdint.h>

// Problem constants
//  SEQ=1024 (32x32), BSZ=8, EMBED=1024, KD=64, NDIM=16, V=64, R=16384, R2=16
//  DIRS=4, H=64, CDIM=4096

typedef __attribute__((ext_vector_type(8))) short short8;   // 8 bf16 (4 VGPRs)
typedef __attribute__((ext_vector_type(4))) float f32x4;    // MFMA accumulator

__device__ inline uint16_t f2bf(float f) {   // fp32 -> bf16 RNE
    uint32_t u = __float_as_uint(f);
    uint32_t r = (u + 0x7FFFu + ((u >> 16) & 1u)) >> 16;
    return (uint16_t)r;
}
__device__ inline float bf2f(uint16_t v) {
    return __uint_as_float((uint32_t)v << 16);
}
__device__ inline uint32_t packbf(float a, float b) {
    return (uint32_t)f2bf(a) | ((uint32_t)f2bf(b) << 16);
}

// ---------------------------------------------------------------------------
// K_sel: per (d,r) extract one-hot indices of one_matrix rows.
// ---------------------------------------------------------------------------
__global__ __launch_bounds__(256) void k_sel(const float* __restrict__ om,
                                             uint32_t* __restrict__ sel,
                                             float* __restrict__ coef) {
    int gw = (blockIdx.x * 256 + threadIdx.x) >> 6;
    int lane = threadIdx.x & 63;
    int nw = gridDim.x * 4;
    for (int pr = gw; pr < 32768; pr += nw) {
        int d = pr >> 14, r = pr & 16383;
        uint32_t s = 0;
        float cf = 1.0f;
        #pragma unroll
        for (int a = 0; a < 5; ++a) {
            float v = om[((size_t)(d * 5 + a) * 16384 + r) * 64 + lane];
            unsigned long long m = __ballot(v != 0.0f);
            int idx = (m != 0ull) ? __builtin_ctzll(m) : 0;
            float mv = __shfl(v, idx, 64);
            if (m == 0ull) mv = 0.0f;
            if (a < 4) {
                s |= (uint32_t)idx << (6 * a);
                cf *= mv;
            } else {
                if (idx > 1) cf = 0.0f;
                else { s |= (uint32_t)idx << 24; cf *= mv; }
            }
        }
        if (lane == 0) { sel[pr] = s; coef[pr] = cf; }
    }
}

// ---------------------------------------------------------------------------
// K_w: w[d][p][kn] = sum_{r2} coef * exp2(sum_a v_a*log2sig(A_a)) * sig(B_col)
//   NOTE: B select is branch-free arithmetic (c0/c1 masks) — a runtime-indexed
//   private array here gets demoted to LDS (PromoteAlloca) and was the R3
//   58-us pathology (LDS_Block_Size=16384, 2e6 bank-conflict cycles).
// ---------------------------------------------------------------------------
__global__ __launch_bounds__(256) void k_w(const float* __restrict__ A,
                                           const float* __restrict__ B1,
                                           const float* __restrict__ B2,
                                           const uint32_t* __restrict__ sel,
                                           const float* __restrict__ coef,
                                           float* __restrict__ w) {
    int p = blockIdx.x;
    int t = threadIdx.x;
    int d = __builtin_amdgcn_readfirstlane(t >> 7);   // wave-uniform -> s_load
    int j0 = (t & 127) * 8;

    float L0[8], L1[8], L2[8], L3[8], B0v[8], B1v[8], acc[8];
    {
        #pragma unroll
        for (int a = 0; a < 4; ++a) {
            float* La = (a == 0) ? L0 : (a == 1) ? L1 : (a == 2) ? L2 : L3;
            float4 u0 = *(const float4*)(A + a * 1024 + j0);
            float4 u1 = *(const float4*)(A + a * 1024 + j0 + 4);
            float tmp[8] = {u0.x, u0.y, u0.z, u0.w, u1.x, u1.y, u1.z, u1.w};
            #pragma unroll
            for (int jj = 0; jj < 8; ++jj)
                La[jj] = -log2f(1.0f + expf(-tmp[jj]));
        }
        float4 u0 = *(const float4*)(B1 + j0);
        float4 u1 = *(const float4*)(B1 + j0 + 4);
        float4 v0 = *(const float4*)(B2 + j0);
        float4 v1 = *(const float4*)(B2 + j0 + 4);
        float t1[8] = {u0.x, u0.y, u0.z, u0.w, u1.x, u1.y, u1.z, u1.w};
        float t2[8] = {v0.x, v0.y, v0.z, v0.w, v1.x, v1.y, v1.z, v1.w};
        #pragma unroll
        for (int jj = 0; jj < 8; ++jj) {
            B0v[jj] = 1.0f / (1.0f + expf(-t1[jj]));
            B1v[jj] = 1.0f / (1.0f + expf(-t2[jj]));
        }
    }
    #pragma unroll
    for (int jj = 0; jj < 8; ++jj) acc[jj] = 0.0f;

    int base = d * 16384 + p * 16;
    #pragma unroll
    for (int r2 = 0; r2 < 16; ++r2) {
        uint32_t s = sel[base + r2];
        float cf = coef[base + r2];
        float f0 = (float)(s & 63u);
        float f1 = (float)((s >> 6) & 63u);
        float f2 = (float)((s >> 12) & 63u);
        float f3 = (float)((s >> 18) & 63u);
        int col = (int)((s >> 24) & 1u);
        float c0 = col ? 0.0f : cf;
        float c1 = col ? cf : 0.0f;
        #pragma unroll
        for (int jj = 0; jj < 8; ++jj) {
            float ex = __builtin_fmaf(f3, L3[jj],
                       __builtin_fmaf(f2, L2[jj],
                       __builtin_fmaf(f1, L1[jj], f0 * L0[jj])));
            float bs = __builtin_fmaf(c1, B1v[jj], c0 * B0v[jj]);
            acc[jj] = __builtin_fmaf(exp2f(ex), bs, acc[jj]);
        }
    }
    float* dst = w + (size_t)(d * 1024 + p) * 1024 + j0;
    *(float4*)(dst)     = make_float4(acc[0], acc[1], acc[2], acc[3]);
    *(float4*)(dst + 4) = make_float4(acc[4], acc[5], acc[6], acc[7]);
}

// ---------------------------------------------------------------------------
// K_kd: kd4b[dir][e][p] (bf16) = boundary(p) * sum_{d,n} w*C/4
// ---------------------------------------------------------------------------
__global__ __launch_bounds__(256) void k_kd(const float* __restrict__ w,
                                            const float* __restrict__ C1,
                                            const float* __restrict__ C2,
                                            uint16_t* __restrict__ kd4b) {
    __shared__ float Wl[128 * 33];
    __shared__ float Ctl[32 * 65];
    int kap = blockIdx.x;
    int p0 = blockIdx.y * 128;
    int dir = kap >> 4, m = kap & 15;
    int t = threadIdx.x;

    {
        int d = t >> 7, pp = t & 127;
        const float* src = w + ((size_t)(d * 1024 + p0 + pp) * 64 + kap) * 16;
        float* dst = Wl + pp * 33 + d * 16;
        #pragma unroll
        for (int q = 0; q < 4; ++q) {
            float4 v = *(const float4*)(src + q * 4);
            dst[q * 4 + 0] = v.x; dst[q * 4 + 1] = v.y;
            dst[q * 4 + 2] = v.z; dst[q * 4 + 3] = v.w;
        }
    }
    if (t < 128) {
        int d = t >> 6, h = t & 63;
        const float* Cd = d ? C2 : C1;
        const float* src = Cd + (size_t)(h * 64 + kap) * 16;
        #pragma unroll
        for (int q = 0; q < 16; ++q)
            Ctl[(d * 16 + q) * 65 + h] = src[q] * 0.25f;
    }
    __syncthreads();

    int ph = t & 15, hq = t >> 4;
    int pl = ph * 8, h0 = hq * 4;
    float acc[8][4];
    #pragma unroll
    for (int i = 0; i < 8; ++i)
        { acc[i][0] = acc[i][1] = acc[i][2] = acc[i][3] = 0.0f; }

    for (int k = 0; k < 32; ++k) {
        float c0 = Ctl[k * 65 + h0 + 0];
        float c1 = Ctl[k * 65 + h0 + 1];
        float c2 = Ctl[k * 65 + h0 + 2];
        float c3 = Ctl[k * 65 + h0 + 3];
        #pragma unroll
        for (int i = 0; i < 8; ++i) {
            float wv = Wl[(pl + i) * 33 + k];
            acc[i][0] += wv * c0; acc[i][1] += wv * c1;
            acc[i][2] += wv * c2; acc[i][3] += wv * c3;
        }
    }
    #pragma unroll
    for (int j = 0; j < 4; ++j) {
        int h = h0 + j;
        uint32_t pk[4];
        #pragma unroll
        for (int qq = 0; qq < 4; ++qq) {
            float v0, v1;
            #pragma unroll
            for (int z = 0; z < 2; ++z) {
                int p = p0 + pl + qq * 2 + z;
                int ii = p >> 5, jj = p & 31;
                float f = ((ii == 0) != (jj == 0)) ? 2.0f : 1.0f;
                float val = acc[qq * 2 + z][j] * f;
                if (z == 0) v0 = val; else v1 = val;
            }
            pk[qq] = packbf(v0, v1);
        }
        uint16_t* dst = kd4b + ((size_t)(dir * 1024 + h * 16 + m)) * 1024 + p0 + pl;
        *(uint4*)dst = make_uint4(pk[0], pk[1], pk[2], pk[3]);
    }
}

// ---------------------------------------------------------------------------
// K_t1: xtb[e][u][b][v] (bf16) = x[u*32+v][b][e] — packed in conv's LDS layout
// ---------------------------------------------------------------------------
__global__ __launch_bounds__(256) void k_t1(const float* __restrict__ x,
                                            uint16_t* __restrict__ xtb) {
    __shared__ float tile[256 * 36];   // [pv=v*8+b][ec], stride 36 (bank-safe both phases)
    int u = blockIdx.x, e0 = blockIdx.y * 32;
    int t = threadIdx.x;
    int ec = t & 31, vb = t >> 5;
    for (int c = 0; c < 32; ++c) {
        int pv = c * 8 + vb;               // v = pv>>3, b = pv&7
        int v = pv >> 3, b = pv & 7;
        tile[pv * 36 + ec] = x[(size_t)((u * 32 + v) * 8 + b) * 1024 + e0 + ec];
    }
    __syncthreads();
    int er = t >> 3, seg = t & 7;          // e-row within tile, b = seg
    uint32_t pk[16];
    #pragma unroll
    for (int k2 = 0; k2 < 16; ++k2) {
        float f0 = tile[((2 * k2) * 8 + seg) * 36 + er];
        float f1 = tile[((2 * k2 + 1) * 8 + seg) * 36 + er];
        pk[k2] = packbf(f0, f1);
    }
    uint16_t* dst = xtb + (size_t)(e0 + er) * 8192 + u * 256 + seg * 32;
    uint4* d4 = (uint4*)dst;
    d4[0] = make_uint4(pk[0], pk[1], pk[2], pk[3]);
    d4[1] = make_uint4(pk[4], pk[5], pk[6], pk[7]);
    d4[2] = make_uint4(pk[8], pk[9], pk[10], pk[11]);
    d4[3] = make_uint4(pk[12], pk[13], pk[14], pk[15]);
}

// ---------------------------------------------------------------------------
// K_conv (MFMA): per-channel causal 2D conv as Toeplitz GEMM.
//   Krev[di][s(8)][c(48, stride 52 shorts)] bf16: Krev[di][s][c] = kimg[di][31+s-c]
//   Xt[u(32)][b(8)][v(32)] bf16 staged by plain 16B/lane copies (pre-packed xtb).
//   Static unrolled (g,dd) schedule; rows u<16 register-cached.
// ---------------------------------------------------------------------------
__global__ __launch_bounds__(256) void k_conv(const uint16_t* __restrict__ xtb,
                                              const uint16_t* __restrict__ kd4b,
                                              float* __restrict__ yt) {
    __shared__ __align__(16) char smem[26624 + 16384];  // Krev 26624 + Xt 16384
    const int KROW = 832;   // 8 s-rows * 104 B
    const int SROW = 104;   // 52 shorts per s-row (48 used + 4 pad)
    char* xtl = smem + 26624;

    int e = blockIdx.x;
    int t = threadIdx.x;
    int lane = t & 63, wv = t >> 6;
    int n = lane & 15, q = lane >> 4, nn = n & 7;

    // zero Krev (26624 B = 1664 x 16B)
    {
        f32x4 z = {0.f, 0.f, 0.f, 0.f};
        for (int idx = t; idx < 1664; idx += 256)
            *(f32x4*)(smem + idx * 16) = z;
    }
    // stage Xt: 16 KB contiguous copy (conflict-free, no repack)
    {
        const uint4* src = (const uint4*)(xtb + (size_t)e * 8192);
        #pragma unroll
        for (int r = 0; r < 4; ++r) {
            uint4 v = src[r * 256 + t];
            *(uint4*)(xtl + (r * 256 + t) * 16) = v;
        }
    }
    // flip-sum 4 kernel pixels
    int pi = t >> 3, pj = (t & 7) * 4;
    float s0, s1, s2, s3;
    {
        const uint16_t* b0 = kd4b + (size_t)e * 1024;
        ushort4 a0 = *(const ushort4*)(b0 + pi * 32 + pj);
        ushort4 a1 = *(const ushort4*)(b0 + (1 << 20) + (31 - pi) * 32 + pj);
        ushort4 a2 = *(const ushort4*)(b0 + (2 << 20) + pi * 32 + (28 - pj));
        ushort4 a3 = *(const ushort4*)(b0 + (3 << 20) + (31 - pi) * 32 + (28 - pj));
        s0 = bf2f(a0.x) + bf2f(a1.x) + bf2f(a2.w) + bf2f(a3.w);
        s1 = bf2f(a0.y) + bf2f(a1.y) + bf2f(a2.z) + bf2f(a3.z);
        s2 = bf2f(a0.z) + bf2f(a1.z) + bf2f(a2.y) + bf2f(a3.y);
        s3 = bf2f(a0.w) + bf2f(a1.w) + bf2f(a2.x) + bf2f(a3.x);
    }
    __syncthreads();   // zeroing complete

    // scatter into 8 shift-staggered reversed copies
    {
        uint16_t k0 = f2bf(s0), k1 = f2bf(s1), k2 = f2bf(s2), k3 = f2bf(s3);
        #pragma unroll
        for (int s = 0; s < 8; ++s) {
            uint16_t* row = (uint16_t*)(smem + pi * KROW + s * SROW);
            int c = 31 + s - pj;           // c-3..c within [s, 38] ⊂ [0,48)
            row[c]     = k0;
            row[c - 1] = k1;
            row[c - 2] = k2;
            row[c - 3] = k3;
        }
    }
    __syncthreads();

    // lane offsets into Krev rows (16B-aligned by construction of sh)
    int A0 = n - 8 * q;          // tile0 leading index; < -8 => all-zero fragment
    int A1 = A0 + 16;            // tile1, always in [-8, 31]
    int sh1 = (A1 + 9) & 7;
    int off1 = sh1 * SROW + (31 + sh1 - A1) * 2;
    int off0;
    if (A0 >= -8) {
        int sh0 = (A0 + 9) & 7;
        off0 = sh0 * SROW + (31 + sh0 - A0) * 2;
    } else {
        off0 = 80;               // s=0, c=40..47: guaranteed-zero 16B region
    }
    int boff = nn * 64 + q * 16;

    // register-cache input rows 0..15
    short8 Breg[16];
    #pragma unroll
    for (int u = 0; u < 16; ++u)
        Breg[u] = *(const short8*)(xtl + u * 512 + boff);

    f32x4 acc0[8], acc1[8];
    #pragma unroll
    for (int ii = 0; ii < 8; ++ii) {
        acc0[ii] = (f32x4){0.f, 0.f, 0.f, 0.f};
        acc1[ii] = (f32x4){0.f, 0.f, 0.f, 0.f};
    }

    // phase 1: di = wv-dd (dd=0..wv), all 8 ii active, u = dd+4*ii
    #pragma unroll
    for (int dd = 0; dd < 4; ++dd) {
        if (dd <= wv) {
            const char* krow = smem + (wv - dd) * KROW;
            short8 a0 = *(const short8*)(krow + off0);
            short8 a1 = *(const short8*)(krow + off1);
            #pragma unroll
            for (int ii = 0; ii < 8; ++ii) {
                short8 bb = (ii < 4) ? Breg[dd + 4 * ii]
                                     : *(const short8*)(xtl + (dd + 4 * ii) * 512 + boff);
                acc0[ii] = __builtin_amdgcn_mfma_f32_16x16x32_bf16(a0, bb, acc0[ii], 0, 0, 0);
                acc1[ii] = __builtin_amdgcn_mfma_f32_16x16x32_bf16(a1, bb, acc1[ii], 0, 0, 0);
            }
        }
    }
    // phase 2: g=1..7, dd=0..3: di = wv+4g-3+dd, ii = g..7, u = 4(ii-g)+3-dd
    #pragma unroll
    for (int g = 1; g <= 7; ++g) {
        #pragma unroll
        for (int dd = 0; dd < 4; ++dd) {
            const char* krow = smem + (wv + 4 * g - 3 + dd) * KROW;
            short8 a0 = *(const short8*)(krow + off0);
            short8 a1 = *(const short8*)(krow + off1);
            #pragma unroll
            for (int ii = g; ii < 8; ++ii) {
                int u = 4 * (ii - g) + 3 - dd;
                short8 bb = (ii - g < 4) ? Breg[u]
                                         : *(const short8*)(xtl + u * 512 + boff);
                acc0[ii] = __builtin_amdgcn_mfma_f32_16x16x32_bf16(a0, bb, acc0[ii], 0, 0, 0);
                acc1[ii] = __builtin_amdgcn_mfma_f32_16x16x32_bf16(a1, bb, acc1[ii], 0, 0, 0);
            }
        }
    }

    // epilogue: direct stores.  D row m=4q+r -> p = i*32 + tile*16 + 4q+r, col n = b
    if (n < 8) {
        float* base = yt + ((size_t)(n * 1024 + e)) * 1024 + q * 4;
        #pragma unroll
        for (int ii = 0; ii < 8; ++ii) {
            int i = wv + 4 * ii;
            *(float4*)(base + i * 32)      = *(float4*)&acc0[ii];
            *(float4*)(base + i * 32 + 16) = *(float4*)&acc1[ii];
        }
    }
}

// ---------------------------------------------------------------------------
// K_t2: out[p][b][e] = yt[b][e][p] + x[p][b][e]*omega[e]
// ---------------------------------------------------------------------------
__global__ __launch_bounds__(256) void k_t2(const float* __restrict__ yt,
                                            const float* __restrict__ x,
                                            const float* __restrict__ omega,
                                            float* __restrict__ out) {
    __shared__ float tile[32][33];
    int e0 = blockIdx.x * 32, p0 = blockIdx.y * 32, b = blockIdx.z;
    int c = threadIdx.x & 31, r4 = (threadIdx.x >> 5) * 4;
    #pragma unroll
    for (int q = 0; q < 4; ++q)
        tile[r4 + q][c] = yt[(size_t)(b * 1024 + e0 + r4 + q) * 1024 + p0 + c];
    __syncthreads();
    #pragma unroll
    for (int q = 0; q < 4; ++q) {
        int p = p0 + r4 + q, e = e0 + c;
        size_t oi = (size_t)(p * 8 + b) * 1024 + e;
        out[oi] = tile[c][r4 + q] + x[oi] * omega[e];
    }
}

// ---------------------------------------------------------------------------
extern "C" void kernel_launch(void* const* d_in, const int* in_sizes, int n_in,
                              void* d_out, int out_size, void* d_ws, size_t ws_size,
                              hipStream_t stream) {
    (void)in_sizes; (void)n_in; (void)out_size; (void)ws_size;
    const float* x   = (const float*)d_in[0];
    const float* A   = (const float*)d_in[1];
    const float* B1  = (const float*)d_in[2];
    const float* B2  = (const float*)d_in[3];
    const float* C1  = (const float*)d_in[4];
    const float* C2  = (const float*)d_in[5];
    const float* omg = (const float*)d_in[6];
    const float* om  = (const float*)d_in[7];
    float* out = (float*)d_out;

    float* ws  = (float*)d_ws;
    uint16_t* xtb  = (uint16_t*)ws;                 // 8M shorts (16 MB) = 4M float slots
    uint16_t* kd4b = (uint16_t*)(ws + 4194304);     // 4M shorts (8 MB)  = 2M float slots
    float* yt = ws + 6291456;                       // 8M floats (32 MB)
    // smalls carved inside yt region (dead before k_conv writes yt):
    uint32_t* sel = (uint32_t*)yt;                  // 32768 u32
    float* coef = (float*)(sel + 32768);            // 32768
    float* w    = coef + 32768;                     // 2,097,152

    k_t1  <<<dim3(32, 32), 256, 0, stream>>>(x, xtb);
    k_sel <<<256, 256, 0, stream>>>(om, sel, coef);
    k_w   <<<1024, 256, 0, stream>>>(A, B1, B2, sel, coef, w);
    k_kd  <<<dim3(64, 8), 256, 0, stream>>>(w, C1, C2, kd4b);
    k_conv<<<1024, 256, 0, stream>>>(xtb, kd4b, yt);
    k_t2  <<<dim3(32, 32, 8), 256, 0, stream>>>(yt, x, omg, out);
}

// Round 5
// 220.453 us; speedup vs baseline: 1.6422x; 1.1001x over previous
//
#include <hip/hip_runtime.h>
#include <stdint.h>

// Problem constants
//  SEQ=1024 (32x32), BSZ=8, EMBED=1024, KD=64, NDIM=16, V=64, R=16384, R2=16
//  DIRS=4, H=64, CDIM=4096

typedef __attribute__((ext_vector_type(8))) short short8;   // 8 bf16 (4 VGPRs)
typedef __attribute__((ext_vector_type(4))) float f32x4;    // MFMA accumulator

__device__ inline uint16_t f2bf(float f) {   // fp32 -> bf16 RNE
    uint32_t u = __float_as_uint(f);
    uint32_t r = (u + 0x7FFFu + ((u >> 16) & 1u)) >> 16;
    return (uint16_t)r;
}
__device__ inline float bf2f(uint16_t v) {
    return __uint_as_float((uint32_t)v << 16);
}
__device__ inline uint32_t packbf(float a, float b) {
    return (uint32_t)f2bf(a) | ((uint32_t)f2bf(b) << 16);
}

// ---------------------------------------------------------------------------
// K_sel: per (d,r) extract one-hot indices of one_matrix rows.
//   Grid = 2048 blocks (was 256: only 1 wave/SIMD -> latency-bound).
// ---------------------------------------------------------------------------
__global__ __launch_bounds__(256) void k_sel(const float* __restrict__ om,
                                             uint32_t* __restrict__ sel,
                                             float* __restrict__ coef) {
    int gw = (blockIdx.x * 256 + threadIdx.x) >> 6;
    int lane = threadIdx.x & 63;
    int nw = gridDim.x * 4;
    for (int pr = gw; pr < 32768; pr += nw) {
        int d = pr >> 14, r = pr & 16383;
        uint32_t s = 0;
        float cf = 1.0f;
        #pragma unroll
        for (int a = 0; a < 5; ++a) {
            float v = om[((size_t)(d * 5 + a) * 16384 + r) * 64 + lane];
            unsigned long long m = __ballot(v != 0.0f);
            int idx = (m != 0ull) ? __builtin_ctzll(m) : 0;
            float mv = __shfl(v, idx, 64);
            if (m == 0ull) mv = 0.0f;
            if (a < 4) {
                s |= (uint32_t)idx << (6 * a);
                cf *= mv;
            } else {
                if (idx > 1) cf = 0.0f;
                else { s |= (uint32_t)idx << 24; cf *= mv; }
            }
        }
        if (lane == 0) { sel[pr] = s; coef[pr] = cf; }
    }
}

// ---------------------------------------------------------------------------
// K_w: w[d][p][kn] = sum_{r2} coef * exp2(sum_a v_a*log2sig(A_a)) * sig(B_col)
//   B select is branch-free (runtime-indexed private arrays get demoted to
//   LDS by PromoteAlloca -> was the R3 58-us pathology).
// ---------------------------------------------------------------------------
__global__ __launch_bounds__(256) void k_w(const float* __restrict__ A,
                                           const float* __restrict__ B1,
                                           const float* __restrict__ B2,
                                           const uint32_t* __restrict__ sel,
                                           const float* __restrict__ coef,
                                           float* __restrict__ w) {
    int p = blockIdx.x;
    int t = threadIdx.x;
    int d = __builtin_amdgcn_readfirstlane(t >> 7);   // wave-uniform -> s_load
    int j0 = (t & 127) * 8;

    float L0[8], L1[8], L2[8], L3[8], B0v[8], B1v[8], acc[8];
    {
        #pragma unroll
        for (int a = 0; a < 4; ++a) {
            float* La = (a == 0) ? L0 : (a == 1) ? L1 : (a == 2) ? L2 : L3;
            float4 u0 = *(const float4*)(A + a * 1024 + j0);
            float4 u1 = *(const float4*)(A + a * 1024 + j0 + 4);
            float tmp[8] = {u0.x, u0.y, u0.z, u0.w, u1.x, u1.y, u1.z, u1.w};
            #pragma unroll
            for (int jj = 0; jj < 8; ++jj)
                La[jj] = -log2f(1.0f + expf(-tmp[jj]));
        }
        float4 u0 = *(const float4*)(B1 + j0);
        float4 u1 = *(const float4*)(B1 + j0 + 4);
        float4 v0 = *(const float4*)(B2 + j0);
        float4 v1 = *(const float4*)(B2 + j0 + 4);
        float t1[8] = {u0.x, u0.y, u0.z, u0.w, u1.x, u1.y, u1.z, u1.w};
        float t2[8] = {v0.x, v0.y, v0.z, v0.w, v1.x, v1.y, v1.z, v1.w};
        #pragma unroll
        for (int jj = 0; jj < 8; ++jj) {
            B0v[jj] = 1.0f / (1.0f + expf(-t1[jj]));
            B1v[jj] = 1.0f / (1.0f + expf(-t2[jj]));
        }
    }
    #pragma unroll
    for (int jj = 0; jj < 8; ++jj) acc[jj] = 0.0f;

    int base = d * 16384 + p * 16;
    #pragma unroll
    for (int r2 = 0; r2 < 16; ++r2) {
        uint32_t s = sel[base + r2];
        float cf = coef[base + r2];
        float f0 = (float)(s & 63u);
        float f1 = (float)((s >> 6) & 63u);
        float f2 = (float)((s >> 12) & 63u);
        float f3 = (float)((s >> 18) & 63u);
        int col = (int)((s >> 24) & 1u);
        float c0 = col ? 0.0f : cf;
        float c1 = col ? cf : 0.0f;
        #pragma unroll
        for (int jj = 0; jj < 8; ++jj) {
            float ex = __builtin_fmaf(f3, L3[jj],
                       __builtin_fmaf(f2, L2[jj],
                       __builtin_fmaf(f1, L1[jj], f0 * L0[jj])));
            float bs = __builtin_fmaf(c1, B1v[jj], c0 * B0v[jj]);
            acc[jj] = __builtin_fmaf(exp2f(ex), bs, acc[jj]);
        }
    }
    float* dst = w + (size_t)(d * 1024 + p) * 1024 + j0;
    *(float4*)(dst)     = make_float4(acc[0], acc[1], acc[2], acc[3]);
    *(float4*)(dst + 4) = make_float4(acc[4], acc[5], acc[6], acc[7]);
}

// ---------------------------------------------------------------------------
// K_kd: kd4b[dir][e][p] (bf16) = boundary(p) * sum_{d,n} w*C/4
// ---------------------------------------------------------------------------
__global__ __launch_bounds__(256) void k_kd(const float* __restrict__ w,
                                            const float* __restrict__ C1,
                                            const float* __restrict__ C2,
                                            uint16_t* __restrict__ kd4b) {
    __shared__ float Wl[128 * 33];
    __shared__ float Ctl[32 * 65];
    int kap = blockIdx.x;
    int p0 = blockIdx.y * 128;
    int dir = kap >> 4, m = kap & 15;
    int t = threadIdx.x;

    {
        int d = t >> 7, pp = t & 127;
        const float* src = w + ((size_t)(d * 1024 + p0 + pp) * 64 + kap) * 16;
        float* dst = Wl + pp * 33 + d * 16;
        #pragma unroll
        for (int q = 0; q < 4; ++q) {
            float4 v = *(const float4*)(src + q * 4);
            dst[q * 4 + 0] = v.x; dst[q * 4 + 1] = v.y;
            dst[q * 4 + 2] = v.z; dst[q * 4 + 3] = v.w;
        }
    }
    if (t < 128) {
        int d = t >> 6, h = t & 63;
        const float* Cd = d ? C2 : C1;
        const float* src = Cd + (size_t)(h * 64 + kap) * 16;
        #pragma unroll
        for (int q = 0; q < 16; ++q)
            Ctl[(d * 16 + q) * 65 + h] = src[q] * 0.25f;
    }
    __syncthreads();

    int ph = t & 15, hq = t >> 4;
    int pl = ph * 8, h0 = hq * 4;
    float acc[8][4];
    #pragma unroll
    for (int i = 0; i < 8; ++i)
        { acc[i][0] = acc[i][1] = acc[i][2] = acc[i][3] = 0.0f; }

    for (int k = 0; k < 32; ++k) {
        float c0 = Ctl[k * 65 + h0 + 0];
        float c1 = Ctl[k * 65 + h0 + 1];
        float c2 = Ctl[k * 65 + h0 + 2];
        float c3 = Ctl[k * 65 + h0 + 3];
        #pragma unroll
        for (int i = 0; i < 8; ++i) {
            float wv = Wl[(pl + i) * 33 + k];
            acc[i][0] += wv * c0; acc[i][1] += wv * c1;
            acc[i][2] += wv * c2; acc[i][3] += wv * c3;
        }
    }
    #pragma unroll
    for (int j = 0; j < 4; ++j) {
        int h = h0 + j;
        uint32_t pk[4];
        #pragma unroll
        for (int qq = 0; qq < 4; ++qq) {
            float v0, v1;
            #pragma unroll
            for (int z = 0; z < 2; ++z) {
                int p = p0 + pl + qq * 2 + z;
                int ii = p >> 5, jj = p & 31;
                float f = ((ii == 0) != (jj == 0)) ? 2.0f : 1.0f;
                float val = acc[qq * 2 + z][j] * f;
                if (z == 0) v0 = val; else v1 = val;
            }
            pk[qq] = packbf(v0, v1);
        }
        uint16_t* dst = kd4b + ((size_t)(dir * 1024 + h * 16 + m)) * 1024 + p0 + pl;
        *(uint4*)dst = make_uint4(pk[0], pk[1], pk[2], pk[3]);
    }
}

// ---------------------------------------------------------------------------
// K_t1: xtb[e][u][b][v] (bf16) = x[u*32+v][b][e]
//   Phase A: thread t owns x row (u*256+t): 128 B contiguous float4 loads.
//   Phase B: thread (er=t&31, b=t>>5) packs 32 v (stride-8 LDS reads,
//   conflict-free: bank = (er + v*8 + b) % 32 distinct per er).
// ---------------------------------------------------------------------------
__global__ __launch_bounds__(256) void k_t1(const float* __restrict__ x,
                                            uint16_t* __restrict__ xtb) {
    __shared__ float lds[32 * 257];    // [ec][vb], pad 257
    int u = blockIdx.x, e0 = blockIdx.y * 32;
    int t = threadIdx.x;
    {
        const float* src = x + (size_t)(u * 256 + t) * 1024 + e0;
        #pragma unroll
        for (int qq = 0; qq < 8; ++qq) {
            float4 v = *(const float4*)(src + qq * 4);
            lds[(qq * 4 + 0) * 257 + t] = v.x;
            lds[(qq * 4 + 1) * 257 + t] = v.y;
            lds[(qq * 4 + 2) * 257 + t] = v.z;
            lds[(qq * 4 + 3) * 257 + t] = v.w;
        }
    }
    __syncthreads();
    int er = t & 31, b = t >> 5;
    const float* row = lds + er * 257 + b;     // element v at row[v*8]
    uint32_t pk[16];
    #pragma unroll
    for (int k2 = 0; k2 < 16; ++k2)
        pk[k2] = packbf(row[(2 * k2) * 8], row[(2 * k2 + 1) * 8]);
    uint16_t* dst = xtb + (size_t)(e0 + er) * 8192 + u * 256 + b * 32;
    uint4* d4 = (uint4*)dst;
    d4[0] = make_uint4(pk[0], pk[1], pk[2], pk[3]);
    d4[1] = make_uint4(pk[4], pk[5], pk[6], pk[7]);
    d4[2] = make_uint4(pk[8], pk[9], pk[10], pk[11]);
    d4[3] = make_uint4(pk[12], pk[13], pk[14], pk[15]);
}

// ---------------------------------------------------------------------------
// K_conv (MFMA): per-channel causal 2D conv as Toeplitz GEMM.
//   Krev[di][s(8)][c(48, stride 52 shorts)] bf16: Krev[di][s][c] = kimg[di][31+s-c]
//   Xt[u(32)][b(8)][v(32)] bf16 staged by plain 16B/lane copies (pre-packed xtb).
//   Static unrolled (g,dd) schedule; rows u<16 register-cached.
//   Output yt is bf16 (halves the 32 MB write; t2 re-reads it once).
// ---------------------------------------------------------------------------
__global__ __launch_bounds__(256) void k_conv(const uint16_t* __restrict__ xtb,
                                              const uint16_t* __restrict__ kd4b,
                                              uint16_t* __restrict__ ytb) {
    __shared__ __align__(16) char smem[26624 + 16384];  // Krev 26624 + Xt 16384
    const int KROW = 832;   // 8 s-rows * 104 B
    const int SROW = 104;   // 52 shorts per s-row (48 used + 4 pad)
    char* xtl = smem + 26624;

    int e = blockIdx.x;
    int t = threadIdx.x;
    int lane = t & 63, wv = t >> 6;
    int n = lane & 15, q = lane >> 4, nn = n & 7;

    // zero Krev (26624 B = 1664 x 16B)
    {
        f32x4 z = {0.f, 0.f, 0.f, 0.f};
        for (int idx = t; idx < 1664; idx += 256)
            *(f32x4*)(smem + idx * 16) = z;
    }
    // stage Xt: 16 KB contiguous copy (conflict-free, no repack)
    {
        const uint4* src = (const uint4*)(xtb + (size_t)e * 8192);
        #pragma unroll
        for (int r = 0; r < 4; ++r) {
            uint4 v = src[r * 256 + t];
            *(uint4*)(xtl + (r * 256 + t) * 16) = v;
        }
    }
    // flip-sum 4 kernel pixels
    int pi = t >> 3, pj = (t & 7) * 4;
    float s0, s1, s2, s3;
    {
        const uint16_t* b0 = kd4b + (size_t)e * 1024;
        ushort4 a0 = *(const ushort4*)(b0 + pi * 32 + pj);
        ushort4 a1 = *(const ushort4*)(b0 + (1 << 20) + (31 - pi) * 32 + pj);
        ushort4 a2 = *(const ushort4*)(b0 + (2 << 20) + pi * 32 + (28 - pj));
        ushort4 a3 = *(const ushort4*)(b0 + (3 << 20) + (31 - pi) * 32 + (28 - pj));
        s0 = bf2f(a0.x) + bf2f(a1.x) + bf2f(a2.w) + bf2f(a3.w);
        s1 = bf2f(a0.y) + bf2f(a1.y) + bf2f(a2.z) + bf2f(a3.z);
        s2 = bf2f(a0.z) + bf2f(a1.z) + bf2f(a2.y) + bf2f(a3.y);
        s3 = bf2f(a0.w) + bf2f(a1.w) + bf2f(a2.x) + bf2f(a3.x);
    }
    __syncthreads();   // zeroing complete

    // scatter into 8 shift-staggered reversed copies
    {
        uint16_t k0 = f2bf(s0), k1 = f2bf(s1), k2 = f2bf(s2), k3 = f2bf(s3);
        #pragma unroll
        for (int s = 0; s < 8; ++s) {
            uint16_t* row = (uint16_t*)(smem + pi * KROW + s * SROW);
            int c = 31 + s - pj;           // c-3..c within [s, 38] ⊂ [0,48)
            row[c]     = k0;
            row[c - 1] = k1;
            row[c - 2] = k2;
            row[c - 3] = k3;
        }
    }
    __syncthreads();

    // lane offsets into Krev rows (16B-aligned by construction of sh)
    int A0 = n - 8 * q;          // tile0 leading index; < -8 => all-zero fragment
    int A1 = A0 + 16;            // tile1, always in [-8, 31]
    int sh1 = (A1 + 9) & 7;
    int off1 = sh1 * SROW + (31 + sh1 - A1) * 2;
    int off0;
    if (A0 >= -8) {
        int sh0 = (A0 + 9) & 7;
        off0 = sh0 * SROW + (31 + sh0 - A0) * 2;
    } else {
        off0 = 80;               // s=0, c=40..47: guaranteed-zero 16B region
    }
    int boff = nn * 64 + q * 16;

    // register-cache input rows 0..15
    short8 Breg[16];
    #pragma unroll
    for (int u = 0; u < 16; ++u)
        Breg[u] = *(const short8*)(xtl + u * 512 + boff);

    f32x4 acc0[8], acc1[8];
    #pragma unroll
    for (int ii = 0; ii < 8; ++ii) {
        acc0[ii] = (f32x4){0.f, 0.f, 0.f, 0.f};
        acc1[ii] = (f32x4){0.f, 0.f, 0.f, 0.f};
    }

    // phase 1: di = wv-dd (dd=0..wv), all 8 ii active, u = dd+4*ii
    #pragma unroll
    for (int dd = 0; dd < 4; ++dd) {
        if (dd <= wv) {
            const char* krow = smem + (wv - dd) * KROW;
            short8 a0 = *(const short8*)(krow + off0);
            short8 a1 = *(const short8*)(krow + off1);
            #pragma unroll
            for (int ii = 0; ii < 8; ++ii) {
                short8 bb = (ii < 4) ? Breg[dd + 4 * ii]
                                     : *(const short8*)(xtl + (dd + 4 * ii) * 512 + boff);
                acc0[ii] = __builtin_amdgcn_mfma_f32_16x16x32_bf16(a0, bb, acc0[ii], 0, 0, 0);
                acc1[ii] = __builtin_amdgcn_mfma_f32_16x16x32_bf16(a1, bb, acc1[ii], 0, 0, 0);
            }
        }
    }
    // phase 2: g=1..7, dd=0..3: di = wv+4g-3+dd, ii = g..7, u = 4(ii-g)+3-dd
    #pragma unroll
    for (int g = 1; g <= 7; ++g) {
        #pragma unroll
        for (int dd = 0; dd < 4; ++dd) {
            const char* krow = smem + (wv + 4 * g - 3 + dd) * KROW;
            short8 a0 = *(const short8*)(krow + off0);
            short8 a1 = *(const short8*)(krow + off1);
            #pragma unroll
            for (int ii = g; ii < 8; ++ii) {
                int u = 4 * (ii - g) + 3 - dd;
                short8 bb = (ii - g < 4) ? Breg[u]
                                         : *(const short8*)(xtl + u * 512 + boff);
                acc0[ii] = __builtin_amdgcn_mfma_f32_16x16x32_bf16(a0, bb, acc0[ii], 0, 0, 0);
                acc1[ii] = __builtin_amdgcn_mfma_f32_16x16x32_bf16(a1, bb, acc1[ii], 0, 0, 0);
            }
        }
    }

    // epilogue: bf16 packed stores.  D row m=4q+r -> p = i*32 + tile*16 + 4q+r, col n = b
    if (n < 8) {
        uint16_t* base = ytb + ((size_t)(n * 1024 + e)) * 1024 + q * 4;
        #pragma unroll
        for (int ii = 0; ii < 8; ++ii) {
            int i = wv + 4 * ii;
            uint2 w0 = make_uint2(packbf(acc0[ii][0], acc0[ii][1]),
                                  packbf(acc0[ii][2], acc0[ii][3]));
            uint2 w1 = make_uint2(packbf(acc1[ii][0], acc1[ii][1]),
                                  packbf(acc1[ii][2], acc1[ii][3]));
            *(uint2*)(base + i * 32)      = w0;
            *(uint2*)(base + i * 32 + 16) = w1;
        }
    }
}

// ---------------------------------------------------------------------------
// K_t2: out[p][b][e] = ytb[b][e][p] + x[p][b][e]*omega[e]
//   Block = (e0:32, p0:128, b).  16B/lane ytb loads, LDS transpose, float4 out.
// ---------------------------------------------------------------------------
__global__ __launch_bounds__(256) void k_t2(const uint16_t* __restrict__ ytb,
                                            const float* __restrict__ x,
                                            const float* __restrict__ omega,
                                            float* __restrict__ out) {
    __shared__ float lds[32 * 129];   // [e][pl], pad 129
    int e0 = blockIdx.x * 32, p0 = blockIdx.y * 128, b = blockIdx.z;
    int t = threadIdx.x;
    {
        int er = t & 31, seg = t >> 5;      // 8 chunks of 16 p
        const uint16_t* src = ytb + (size_t)(b * 1024 + e0 + er) * 1024 + p0 + seg * 16;
        uint4 v0 = *(const uint4*)src;
        uint4 v1 = *(const uint4*)(src + 8);
        float* dst = lds + er * 129 + seg * 16;
        uint32_t ww[8] = {v0.x, v0.y, v0.z, v0.w, v1.x, v1.y, v1.z, v1.w};
        #pragma unroll
        for (int k = 0; k < 8; ++k) {
            dst[2 * k]     = bf2f((uint16_t)(ww[k] & 0xFFFFu));
            dst[2 * k + 1] = bf2f((uint16_t)(ww[k] >> 16));
        }
    }
    __syncthreads();
    int pl = t >> 1, eh = (t & 1) * 16;
    int p = p0 + pl;
    const float* xs = x + ((size_t)(p * 8 + b)) * 1024 + e0 + eh;
    float* os = out + ((size_t)(p * 8 + b)) * 1024 + e0 + eh;
    #pragma unroll
    for (int qq = 0; qq < 4; ++qq) {
        float4 xv = *(const float4*)(xs + qq * 4);
        int eb = eh + qq * 4;
        float4 ov;
        ov.x = lds[(eb + 0) * 129 + pl] + xv.x * omega[e0 + eb + 0];
        ov.y = lds[(eb + 1) * 129 + pl] + xv.y * omega[e0 + eb + 1];
        ov.z = lds[(eb + 2) * 129 + pl] + xv.z * omega[e0 + eb + 2];
        ov.w = lds[(eb + 3) * 129 + pl] + xv.w * omega[e0 + eb + 3];
        *(float4*)(os + qq * 4) = ov;
    }
}

// ---------------------------------------------------------------------------
extern "C" void kernel_launch(void* const* d_in, const int* in_sizes, int n_in,
                              void* d_out, int out_size, void* d_ws, size_t ws_size,
                              hipStream_t stream) {
    (void)in_sizes; (void)n_in; (void)out_size; (void)ws_size;
    const float* x   = (const float*)d_in[0];
    const float* A   = (const float*)d_in[1];
    const float* B1  = (const float*)d_in[2];
    const float* B2  = (const float*)d_in[3];
    const float* C1  = (const float*)d_in[4];
    const float* C2  = (const float*)d_in[5];
    const float* omg = (const float*)d_in[6];
    const float* om  = (const float*)d_in[7];
    float* out = (float*)d_out;

    float* ws  = (float*)d_ws;
    uint16_t* xtb  = (uint16_t*)ws;                     // 16 MB
    uint16_t* kd4b = (uint16_t*)(ws + 4194304);         // 8 MB
    uint16_t* ytb  = (uint16_t*)(ws + 6291456);         // 16 MB
    uint32_t* sel  = (uint32_t*)(ws + 10485760);        // 128 KB
    float* coef    = (float*)(sel + 32768);             // 128 KB
    float* w       = coef + 32768;                      // 8 MB  (total ~48.6 MB)

    k_t1  <<<dim3(32, 32), 256, 0, stream>>>(x, xtb);
    k_sel <<<2048, 256, 0, stream>>>(om, sel, coef);
    k_w   <<<1024, 256, 0, stream>>>(A, B1, B2, sel, coef, w);
    k_kd  <<<dim3(64, 8), 256, 0, stream>>>(w, C1, C2, kd4b);
    k_conv<<<1024, 256, 0, stream>>>(xtb, kd4b, ytb);
    k_t2  <<<dim3(32, 8, 8), 256, 0, stream>>>(ytb, x, omg, out);
}

// Round 6
// 197.886 us; speedup vs baseline: 1.8295x; 1.1140x over previous
//
#include <hip/hip_runtime.h>
#include <stdint.h>

// Problem constants
//  SEQ=1024 (32x32), BSZ=8, EMBED=1024, KD=64, NDIM=16, V=64, R=16384, R2=16
//  DIRS=4, H=64, CDIM=4096

typedef __attribute__((ext_vector_type(8))) short short8;   // 8 bf16 (4 VGPRs)
typedef __attribute__((ext_vector_type(4))) float f32x4;    // MFMA accumulator

__device__ inline uint16_t f2bf(float f) {   // fp32 -> bf16 RNE
    uint32_t u = __float_as_uint(f);
    uint32_t r = (u + 0x7FFFu + ((u >> 16) & 1u)) >> 16;
    return (uint16_t)r;
}
__device__ inline float bf2f(uint16_t v) {
    return __uint_as_float((uint32_t)v << 16);
}
__device__ inline uint32_t packbf(float a, float b) {
    return (uint32_t)f2bf(a) | ((uint32_t)f2bf(b) << 16);
}

// ---------------------------------------------------------------------------
// K_front: 2048 blocks.
//   blocks [0,1024):    x transpose/pack  xtb[e][u][b][v] (bf16) = x[p][b][e]
//   blocks [1024,2048): fused sel+w for pixel p = bx-1024:
//     phase 1: 32 ballot-scans of one_matrix rows (this block's own r values)
//     phase 2: w[d][p][kn] = sum_{r2} coef * exp2(sum_a v_a*log2sig(A_a)) * sig(B_col)
//   B select is branch-free (runtime-indexed private arrays get demoted to
//   LDS by PromoteAlloca -> was the R3 58-us pathology).
// ---------------------------------------------------------------------------
__global__ __launch_bounds__(256) void k_front(const float* __restrict__ x,
                                               uint16_t* __restrict__ xtb,
                                               const float* __restrict__ om,
                                               const float* __restrict__ A,
                                               const float* __restrict__ B1,
                                               const float* __restrict__ B2,
                                               float* __restrict__ w) {
    __shared__ __align__(16) float shf[32 * 257];   // t1: transpose tile; selw: sel/coef
    int bx = blockIdx.x;
    int t = threadIdx.x;

    if (bx < 1024) {
        // ---- transpose/pack ----
        int u = bx & 31, e0 = (bx >> 5) * 32;
        {
            const float* src = x + (size_t)(u * 256 + t) * 1024 + e0;
            #pragma unroll
            for (int qq = 0; qq < 8; ++qq) {
                float4 v = *(const float4*)(src + qq * 4);
                shf[(qq * 4 + 0) * 257 + t] = v.x;
                shf[(qq * 4 + 1) * 257 + t] = v.y;
                shf[(qq * 4 + 2) * 257 + t] = v.z;
                shf[(qq * 4 + 3) * 257 + t] = v.w;
            }
        }
        __syncthreads();
        int er = t & 31, b = t >> 5;
        const float* row = shf + er * 257 + b;     // element v at row[v*8]
        uint32_t pk[16];
        #pragma unroll
        for (int k2 = 0; k2 < 16; ++k2)
            pk[k2] = packbf(row[(2 * k2) * 8], row[(2 * k2 + 1) * 8]);
        uint16_t* dst = xtb + (size_t)(e0 + er) * 8192 + u * 256 + b * 32;
        uint4* d4 = (uint4*)dst;
        d4[0] = make_uint4(pk[0], pk[1], pk[2], pk[3]);
        d4[1] = make_uint4(pk[4], pk[5], pk[6], pk[7]);
        d4[2] = make_uint4(pk[8], pk[9], pk[10], pk[11]);
        d4[3] = make_uint4(pk[12], pk[13], pk[14], pk[15]);
    } else {
        // ---- fused sel + w for pixel p ----
        int p = bx - 1024;
        uint32_t* sel_l = (uint32_t*)shf;          // [32]
        float* coef_l = shf + 32;                  // [32]
        int lane = t & 63, wv = t >> 6;

        #pragma unroll
        for (int k = 0; k < 8; ++k) {
            int pi = wv * 8 + k;                   // 0..31
            int d = pi >> 4, r2 = pi & 15;
            int r = p * 16 + r2;
            uint32_t s = 0;
            float cf = 1.0f;
            #pragma unroll
            for (int a = 0; a < 5; ++a) {
                float v = om[((size_t)(d * 5 + a) * 16384 + r) * 64 + lane];
                unsigned long long m = __ballot(v != 0.0f);
                int idx = (m != 0ull) ? __builtin_ctzll(m) : 0;
                float mv = __shfl(v, idx, 64);
                if (m == 0ull) mv = 0.0f;
                if (a < 4) {
                    s |= (uint32_t)idx << (6 * a);
                    cf *= mv;
                } else {
                    if (idx > 1) cf = 0.0f;
                    else { s |= (uint32_t)idx << 24; cf *= mv; }
                }
            }
            if (lane == 0) { sel_l[pi] = s; coef_l[pi] = cf; }
        }
        __syncthreads();

        int d = t >> 7;                            // wave-uniform
        int j0 = (t & 127) * 8;
        float L0[8], L1[8], L2[8], L3[8], B0v[8], B1v[8], acc[8];
        #pragma unroll
        for (int a = 0; a < 4; ++a) {
            float* La = (a == 0) ? L0 : (a == 1) ? L1 : (a == 2) ? L2 : L3;
            float4 u0 = *(const float4*)(A + a * 1024 + j0);
            float4 u1 = *(const float4*)(A + a * 1024 + j0 + 4);
            float tmp[8] = {u0.x, u0.y, u0.z, u0.w, u1.x, u1.y, u1.z, u1.w};
            #pragma unroll
            for (int jj = 0; jj < 8; ++jj)
                La[jj] = -log2f(1.0f + expf(-tmp[jj]));
        }
        {
            float4 u0 = *(const float4*)(B1 + j0);
            float4 u1 = *(const float4*)(B1 + j0 + 4);
            float4 v0 = *(const float4*)(B2 + j0);
            float4 v1 = *(const float4*)(B2 + j0 + 4);
            float t1v[8] = {u0.x, u0.y, u0.z, u0.w, u1.x, u1.y, u1.z, u1.w};
            float t2v[8] = {v0.x, v0.y, v0.z, v0.w, v1.x, v1.y, v1.z, v1.w};
            #pragma unroll
            for (int jj = 0; jj < 8; ++jj) {
                B0v[jj] = 1.0f / (1.0f + expf(-t1v[jj]));
                B1v[jj] = 1.0f / (1.0f + expf(-t2v[jj]));
            }
        }
        #pragma unroll
        for (int jj = 0; jj < 8; ++jj) acc[jj] = 0.0f;

        #pragma unroll
        for (int r2 = 0; r2 < 16; ++r2) {
            uint32_t s = sel_l[d * 16 + r2];
            float cf = coef_l[d * 16 + r2];
            float f0 = (float)(s & 63u);
            float f1 = (float)((s >> 6) & 63u);
            float f2 = (float)((s >> 12) & 63u);
            float f3 = (float)((s >> 18) & 63u);
            int col = (int)((s >> 24) & 1u);
            float c0 = col ? 0.0f : cf;
            float c1 = col ? cf : 0.0f;
            #pragma unroll
            for (int jj = 0; jj < 8; ++jj) {
                float ex = __builtin_fmaf(f3, L3[jj],
                           __builtin_fmaf(f2, L2[jj],
                           __builtin_fmaf(f1, L1[jj], f0 * L0[jj])));
                float bs = __builtin_fmaf(c1, B1v[jj], c0 * B0v[jj]);
                acc[jj] = __builtin_fmaf(exp2f(ex), bs, acc[jj]);
            }
        }
        float* dst = w + (size_t)(d * 1024 + p) * 1024 + j0;
        *(float4*)(dst)     = make_float4(acc[0], acc[1], acc[2], acc[3]);
        *(float4*)(dst + 4) = make_float4(acc[4], acc[5], acc[6], acc[7]);
    }
}

// ---------------------------------------------------------------------------
// K_kd: kd4b[dir][e][p] (bf16) = boundary(p) * sum_{d,n} w*C/4
// ---------------------------------------------------------------------------
__global__ __launch_bounds__(256) void k_kd(const float* __restrict__ w,
                                            const float* __restrict__ C1,
                                            const float* __restrict__ C2,
                                            uint16_t* __restrict__ kd4b) {
    __shared__ float Wl[128 * 33];
    __shared__ float Ctl[32 * 65];
    int kap = blockIdx.x;
    int p0 = blockIdx.y * 128;
    int dir = kap >> 4, m = kap & 15;
    int t = threadIdx.x;

    {
        int d = t >> 7, pp = t & 127;
        const float* src = w + ((size_t)(d * 1024 + p0 + pp) * 64 + kap) * 16;
        float* dst = Wl + pp * 33 + d * 16;
        #pragma unroll
        for (int q = 0; q < 4; ++q) {
            float4 v = *(const float4*)(src + q * 4);
            dst[q * 4 + 0] = v.x; dst[q * 4 + 1] = v.y;
            dst[q * 4 + 2] = v.z; dst[q * 4 + 3] = v.w;
        }
    }
    if (t < 128) {
        int d = t >> 6, h = t & 63;
        const float* Cd = d ? C2 : C1;
        const float* src = Cd + (size_t)(h * 64 + kap) * 16;
        #pragma unroll
        for (int q = 0; q < 16; ++q)
            Ctl[(d * 16 + q) * 65 + h] = src[q] * 0.25f;
    }
    __syncthreads();

    int ph = t & 15, hq = t >> 4;
    int pl = ph * 8, h0 = hq * 4;
    float acc[8][4];
    #pragma unroll
    for (int i = 0; i < 8; ++i)
        { acc[i][0] = acc[i][1] = acc[i][2] = acc[i][3] = 0.0f; }

    for (int k = 0; k < 32; ++k) {
        float c0 = Ctl[k * 65 + h0 + 0];
        float c1 = Ctl[k * 65 + h0 + 1];
        float c2 = Ctl[k * 65 + h0 + 2];
        float c3 = Ctl[k * 65 + h0 + 3];
        #pragma unroll
        for (int i = 0; i < 8; ++i) {
            float wv = Wl[(pl + i) * 33 + k];
            acc[i][0] += wv * c0; acc[i][1] += wv * c1;
            acc[i][2] += wv * c2; acc[i][3] += wv * c3;
        }
    }
    #pragma unroll
    for (int j = 0; j < 4; ++j) {
        int h = h0 + j;
        uint32_t pk[4];
        #pragma unroll
        for (int qq = 0; qq < 4; ++qq) {
            float v0, v1;
            #pragma unroll
            for (int z = 0; z < 2; ++z) {
                int p = p0 + pl + qq * 2 + z;
                int ii = p >> 5, jj = p & 31;
                float f = ((ii == 0) != (jj == 0)) ? 2.0f : 1.0f;
                float val = acc[qq * 2 + z][j] * f;
                if (z == 0) v0 = val; else v1 = val;
            }
            pk[qq] = packbf(v0, v1);
        }
        uint16_t* dst = kd4b + ((size_t)(dir * 1024 + h * 16 + m)) * 1024 + p0 + pl;
        *(uint4*)dst = make_uint4(pk[0], pk[1], pk[2], pk[3]);
    }
}

// ---------------------------------------------------------------------------
// K_conv (MFMA): per-channel causal 2D conv as Toeplitz GEMM.
//   Krev[di(32)][s(8)][c(48 shorts, SROW=96 B)]: Krev[di][s][c] = kimg[di][31+s-c]
//   SROW=96 (mult of 16) => every ds_read_b128 is 16B-aligned; Krev = 24576 B,
//   total LDS 40960 => 4 blocks/CU by LDS.
//   Xt[u(32)][b(8)][v(32)] bf16 staged by 16B/lane copies (pre-packed xtb).
//   Static unrolled (g,dd) schedule; rows u<16 register-cached.
// ---------------------------------------------------------------------------
__global__ __launch_bounds__(256) void k_conv(const uint16_t* __restrict__ xtb,
                                              const uint16_t* __restrict__ kd4b,
                                              uint16_t* __restrict__ ytb) {
    __shared__ __align__(16) char smem[24576 + 16384];  // Krev + Xt
    const int KROW = 768;   // 8 s-rows * 96 B
    const int SROW = 96;    // 48 shorts per s-row, no pad
    char* xtl = smem + 24576;

    int e = blockIdx.x;
    int t = threadIdx.x;
    int lane = t & 63, wv = t >> 6;
    int n = lane & 15, q = lane >> 4, nn = n & 7;

    // zero Krev (24576 B = 1536 x 16B)
    {
        f32x4 z = {0.f, 0.f, 0.f, 0.f};
        #pragma unroll
        for (int k = 0; k < 6; ++k)
            *(f32x4*)(smem + (t + k * 256) * 16) = z;
    }
    // stage Xt: 16 KB contiguous copy
    {
        const uint4* src = (const uint4*)(xtb + (size_t)e * 8192);
        #pragma unroll
        for (int r = 0; r < 4; ++r) {
            uint4 v = src[r * 256 + t];
            *(uint4*)(xtl + (r * 256 + t) * 16) = v;
        }
    }
    // flip-sum 4 kernel pixels
    int pi = t >> 3, pj = (t & 7) * 4;
    float s0, s1, s2, s3;
    {
        const uint16_t* b0 = kd4b + (size_t)e * 1024;
        ushort4 a0 = *(const ushort4*)(b0 + pi * 32 + pj);
        ushort4 a1 = *(const ushort4*)(b0 + (1 << 20) + (31 - pi) * 32 + pj);
        ushort4 a2 = *(const ushort4*)(b0 + (2 << 20) + pi * 32 + (28 - pj));
        ushort4 a3 = *(const ushort4*)(b0 + (3 << 20) + (31 - pi) * 32 + (28 - pj));
        s0 = bf2f(a0.x) + bf2f(a1.x) + bf2f(a2.w) + bf2f(a3.w);
        s1 = bf2f(a0.y) + bf2f(a1.y) + bf2f(a2.z) + bf2f(a3.z);
        s2 = bf2f(a0.z) + bf2f(a1.z) + bf2f(a2.y) + bf2f(a3.y);
        s3 = bf2f(a0.w) + bf2f(a1.w) + bf2f(a2.x) + bf2f(a3.x);
    }
    __syncthreads();   // zeroing complete

    // scatter into 8 shift-staggered reversed copies
    {
        uint16_t k0 = f2bf(s0), k1 = f2bf(s1), k2 = f2bf(s2), k3 = f2bf(s3);
        #pragma unroll
        for (int s = 0; s < 8; ++s) {
            uint16_t* row = (uint16_t*)(smem + pi * KROW + s * SROW);
            int c = 31 + s - pj;           // c-3..c within [s, 31+s] ⊂ [0,48)
            row[c]     = k0;
            row[c - 1] = k1;
            row[c - 2] = k2;
            row[c - 3] = k3;
        }
    }
    __syncthreads();

    // lane offsets into Krev rows (16B-aligned: SROW%16==0 and c0*2%16==0)
    int A0 = n - 8 * q;          // tile0 leading index; < -8 => all-zero fragment
    int A1 = A0 + 16;            // tile1, always in [8, 31]
    int sh1 = (A1 + 9) & 7;
    int off1 = sh1 * SROW + (31 + sh1 - A1) * 2;
    int off0;
    if (A0 >= -8) {
        int sh0 = (A0 + 9) & 7;
        off0 = sh0 * SROW + (31 + sh0 - A0) * 2;
    } else {
        off0 = 80;               // row 0 (s=0), c=40..47: guaranteed-zero 16B
    }
    int boff = nn * 64 + q * 16;

    // register-cache input rows 0..15
    short8 Breg[16];
    #pragma unroll
    for (int u = 0; u < 16; ++u)
        Breg[u] = *(const short8*)(xtl + u * 512 + boff);

    f32x4 acc0[8], acc1[8];
    #pragma unroll
    for (int ii = 0; ii < 8; ++ii) {
        acc0[ii] = (f32x4){0.f, 0.f, 0.f, 0.f};
        acc1[ii] = (f32x4){0.f, 0.f, 0.f, 0.f};
    }

    // phase 1: di = wv-dd (dd=0..wv), all 8 ii active, u = dd+4*ii
    #pragma unroll
    for (int dd = 0; dd < 4; ++dd) {
        if (dd <= wv) {
            const char* krow = smem + (wv - dd) * KROW;
            short8 a0 = *(const short8*)(krow + off0);
            short8 a1 = *(const short8*)(krow + off1);
            #pragma unroll
            for (int ii = 0; ii < 8; ++ii) {
                short8 bb = (ii < 4) ? Breg[dd + 4 * ii]
                                     : *(const short8*)(xtl + (dd + 4 * ii) * 512 + boff);
                acc0[ii] = __builtin_amdgcn_mfma_f32_16x16x32_bf16(a0, bb, acc0[ii], 0, 0, 0);
                acc1[ii] = __builtin_amdgcn_mfma_f32_16x16x32_bf16(a1, bb, acc1[ii], 0, 0, 0);
            }
        }
    }
    // phase 2: g=1..7, dd=0..3: di = wv+4g-3+dd, ii = g..7, u = 4(ii-g)+3-dd
    #pragma unroll
    for (int g = 1; g <= 7; ++g) {
        #pragma unroll
        for (int dd = 0; dd < 4; ++dd) {
            const char* krow = smem + (wv + 4 * g - 3 + dd) * KROW;
            short8 a0 = *(const short8*)(krow + off0);
            short8 a1 = *(const short8*)(krow + off1);
            #pragma unroll
            for (int ii = g; ii < 8; ++ii) {
                int u = 4 * (ii - g) + 3 - dd;
                short8 bb = (ii - g < 4) ? Breg[u]
                                         : *(const short8*)(xtl + u * 512 + boff);
                acc0[ii] = __builtin_amdgcn_mfma_f32_16x16x32_bf16(a0, bb, acc0[ii], 0, 0, 0);
                acc1[ii] = __builtin_amdgcn_mfma_f32_16x16x32_bf16(a1, bb, acc1[ii], 0, 0, 0);
            }
        }
    }

    // epilogue: bf16 packed stores.
    if (n < 8) {
        uint16_t* base = ytb + ((size_t)(n * 1024 + e)) * 1024 + q * 4;
        #pragma unroll
        for (int ii = 0; ii < 8; ++ii) {
            int i = wv + 4 * ii;
            uint2 w0 = make_uint2(packbf(acc0[ii][0], acc0[ii][1]),
                                  packbf(acc0[ii][2], acc0[ii][3]));
            uint2 w1 = make_uint2(packbf(acc1[ii][0], acc1[ii][1]),
                                  packbf(acc1[ii][2], acc1[ii][3]));
            *(uint2*)(base + i * 32)      = w0;
            *(uint2*)(base + i * 32 + 16) = w1;
        }
    }
}

// ---------------------------------------------------------------------------
// K_t2: out[p][b][e] = ytb[b][e][p] + x[p][b][e]*omega[e]
// ---------------------------------------------------------------------------
__global__ __launch_bounds__(256) void k_t2(const uint16_t* __restrict__ ytb,
                                            const float* __restrict__ x,
                                            const float* __restrict__ omega,
                                            float* __restrict__ out) {
    __shared__ float lds[32 * 129];   // [e][pl], pad 129
    int e0 = blockIdx.x * 32, p0 = blockIdx.y * 128, b = blockIdx.z;
    int t = threadIdx.x;
    {
        int er = t & 31, seg = t >> 5;      // 8 chunks of 16 p
        const uint16_t* src = ytb + (size_t)(b * 1024 + e0 + er) * 1024 + p0 + seg * 16;
        uint4 v0 = *(const uint4*)src;
        uint4 v1 = *(const uint4*)(src + 8);
        float* dst = lds + er * 129 + seg * 16;
        uint32_t ww[8] = {v0.x, v0.y, v0.z, v0.w, v1.x, v1.y, v1.z, v1.w};
        #pragma unroll
        for (int k = 0; k < 8; ++k) {
            dst[2 * k]     = bf2f((uint16_t)(ww[k] & 0xFFFFu));
            dst[2 * k + 1] = bf2f((uint16_t)(ww[k] >> 16));
        }
    }
    __syncthreads();
    int pl = t >> 1, eh = (t & 1) * 16;
    int p = p0 + pl;
    const float* xs = x + ((size_t)(p * 8 + b)) * 1024 + e0 + eh;
    float* os = out + ((size_t)(p * 8 + b)) * 1024 + e0 + eh;
    #pragma unroll
    for (int qq = 0; qq < 4; ++qq) {
        float4 xv = *(const float4*)(xs + qq * 4);
        int eb = eh + qq * 4;
        float4 ov;
        ov.x = lds[(eb + 0) * 129 + pl] + xv.x * omega[e0 + eb + 0];
        ov.y = lds[(eb + 1) * 129 + pl] + xv.y * omega[e0 + eb + 1];
        ov.z = lds[(eb + 2) * 129 + pl] + xv.z * omega[e0 + eb + 2];
        ov.w = lds[(eb + 3) * 129 + pl] + xv.w * omega[e0 + eb + 3];
        *(float4*)(os + qq * 4) = ov;
    }
}

// ---------------------------------------------------------------------------
extern "C" void kernel_launch(void* const* d_in, const int* in_sizes, int n_in,
                              void* d_out, int out_size, void* d_ws, size_t ws_size,
                              hipStream_t stream) {
    (void)in_sizes; (void)n_in; (void)out_size; (void)ws_size;
    const float* x   = (const float*)d_in[0];
    const float* A   = (const float*)d_in[1];
    const float* B1  = (const float*)d_in[2];
    const float* B2  = (const float*)d_in[3];
    const float* C1  = (const float*)d_in[4];
    const float* C2  = (const float*)d_in[5];
    const float* omg = (const float*)d_in[6];
    const float* om  = (const float*)d_in[7];
    float* out = (float*)d_out;

    float* ws  = (float*)d_ws;
    uint16_t* xtb  = (uint16_t*)ws;                     // 16 MB
    uint16_t* kd4b = (uint16_t*)(ws + 4194304);         // 8 MB
    uint16_t* ytb  = (uint16_t*)(ws + 6291456);         // 16 MB
    float* w       = ws + 10485760;                     // 8 MB

    k_front<<<2048, 256, 0, stream>>>(x, xtb, om, A, B1, B2, w);
    k_kd   <<<dim3(64, 8), 256, 0, stream>>>(w, C1, C2, kd4b);
    k_conv <<<1024, 256, 0, stream>>>(xtb, kd4b, ytb);
    k_t2   <<<dim3(32, 8, 8), 256, 0, stream>>>(ytb, x, omg, out);
}